// Round 1
// baseline (6358.225 us; speedup 1.0000x reference)
//
#include <hip/hip_runtime.h>
#include <hip/hip_bf16.h>

// PrunedKVAttention: B=2,T=2048,E=1024,H=16,D=64,K_KEEP=391,RECENCY=64
// Round 1: all-f32 correctness baseline. Deterministic (no atomics).

#define TT 2048
#define EE 1024
#define HH 16
#define DD 64
#define KKEEP 391
#define REC 64
#define NBH 32           // B*H
#define QSCALE 0.125f    // D^-0.5

// ---------------- GEMM (NT): C[M,N] = A[M,Kd] * B[N,Kd]^T ----------------
// mode 0: plain C write. mode 1: scatter into Q/K/V [bh][t][d] layouts.
__global__ __launch_bounds__(256) void gemm_nt_f32(
    const float* __restrict__ A, const float* __restrict__ Bw,
    float* __restrict__ Cc, float* __restrict__ Qo, float* __restrict__ Ko,
    float* __restrict__ Vo, int M, int N, int Kd, int mode)
{
  __shared__ float As[16][132];   // transposed store: As[k][m], 132 = 128+4 pad
  __shared__ float Bs[16][132];
  const int tid = threadIdx.x;
  const int m0 = blockIdx.y * 128, n0 = blockIdx.x * 128;
  const int tx = tid & 15, ty = tid >> 4;
  float acc[8][8];
#pragma unroll
  for (int i = 0; i < 8; i++)
#pragma unroll
    for (int j = 0; j < 8; j++) acc[i][j] = 0.f;

  for (int k0 = 0; k0 < Kd; k0 += 16) {
    __syncthreads();
#pragma unroll
    for (int it = 0; it < 2; it++) {
      int idx = it * 256 + tid;
      int r = idx >> 2, c4 = idx & 3;
      float4 av = *reinterpret_cast<const float4*>(&A[(size_t)(m0 + r) * Kd + k0 + c4 * 4]);
      As[c4 * 4 + 0][r] = av.x; As[c4 * 4 + 1][r] = av.y;
      As[c4 * 4 + 2][r] = av.z; As[c4 * 4 + 3][r] = av.w;
      float4 bv = *reinterpret_cast<const float4*>(&Bw[(size_t)(n0 + r) * Kd + k0 + c4 * 4]);
      Bs[c4 * 4 + 0][r] = bv.x; Bs[c4 * 4 + 1][r] = bv.y;
      Bs[c4 * 4 + 2][r] = bv.z; Bs[c4 * 4 + 3][r] = bv.w;
    }
    __syncthreads();
#pragma unroll
    for (int kk = 0; kk < 16; kk++) {
      float4 a0 = *reinterpret_cast<const float4*>(&As[kk][ty * 8]);
      float4 a1 = *reinterpret_cast<const float4*>(&As[kk][ty * 8 + 4]);
      float4 b0 = *reinterpret_cast<const float4*>(&Bs[kk][tx * 8]);
      float4 b1 = *reinterpret_cast<const float4*>(&Bs[kk][tx * 8 + 4]);
      float av[8] = {a0.x, a0.y, a0.z, a0.w, a1.x, a1.y, a1.z, a1.w};
      float bv[8] = {b0.x, b0.y, b0.z, b0.w, b1.x, b1.y, b1.z, b1.w};
#pragma unroll
      for (int i = 0; i < 8; i++)
#pragma unroll
        for (int j = 0; j < 8; j++)
          acc[i][j] = fmaf(av[i], bv[j], acc[i][j]);
    }
  }
  if (mode == 0) {
#pragma unroll
    for (int i = 0; i < 8; i++) {
      size_t base = (size_t)(m0 + ty * 8 + i) * N + n0 + tx * 8;
      *reinterpret_cast<float4*>(&Cc[base]) = make_float4(acc[i][0], acc[i][1], acc[i][2], acc[i][3]);
      *reinterpret_cast<float4*>(&Cc[base + 4]) = make_float4(acc[i][4], acc[i][5], acc[i][6], acc[i][7]);
    }
  } else {
    int n = n0 + tx * 8;
    int p = n >> 10, r = n & 1023;
    int h = r >> 6, d0 = r & 63;
    float* dst = (p == 0) ? Qo : (p == 1) ? Ko : Vo;
#pragma unroll
    for (int i = 0; i < 8; i++) {
      int m = m0 + ty * 8 + i;
      int b = m >> 11, t = m & 2047;
      size_t base = ((size_t)((b * HH + h) * TT + t)) * DD + d0;
      *reinterpret_cast<float4*>(&dst[base]) = make_float4(acc[i][0], acc[i][1], acc[i][2], acc[i][3]);
      *reinterpret_cast<float4*>(&dst[base + 4]) = make_float4(acc[i][4], acc[i][5], acc[i][6], acc[i][7]);
    }
  }
}

// ---------------- Importance: per-(bh) causal softmax column sums ----------------
// grid (qt=32, bh=32); block 256 = 4 waves x 16 rows. Two-sweep flash-style.
// Writes per-block partial colsums part[bh][qt][2048] (deterministic).
__global__ __launch_bounds__(256) void importance_kernel(
    const float* __restrict__ Q, const float* __restrict__ K, float* __restrict__ part)
{
  const int qt = blockIdx.x, bh = blockIdx.y;
  const int tid = threadIdx.x, w = tid >> 6, lane = tid & 63;
  __shared__ float4 Ks4[64 * 16];   // XOR-swizzled K chunk [key][d/4 ^ (key&15)]
  __shared__ float cs[4][2048];     // per-wave colsum slabs
  for (int e = tid; e < 4 * 2048; e += 256) ((float*)cs)[e] = 0.f;

  float m[16], l[16];
#pragma unroll
  for (int rr = 0; rr < 16; rr++) { m[rr] = -3.0e38f; l[rr] = 0.f; }

  const int nch = qt + 1;
  // ---- sweep 1: per-row running max & expsum ----
  for (int ci = 0; ci < nch; ci++) {
    __syncthreads();
#pragma unroll
    for (int it = 0; it < 4; it++) {
      int e = tid + it * 256;
      int krow = e >> 4, c4 = e & 15;
      float4 kv = *reinterpret_cast<const float4*>(&K[((size_t)(bh * TT + ci * 64 + krow)) * DD + c4 * 4]);
      Ks4[(krow << 4) + (c4 ^ (krow & 15))] = kv;
    }
    __syncthreads();
    float4 kreg[16];
#pragma unroll
    for (int i = 0; i < 16; i++) kreg[i] = Ks4[(lane << 4) + (i ^ (lane & 15))];
    const int key = ci * 64 + lane;
#pragma unroll
    for (int rr = 0; rr < 16; rr++) {
      const int row = qt * 64 + w * 16 + rr;
      const float4* q4 = reinterpret_cast<const float4*>(Q) +
                         __builtin_amdgcn_readfirstlane((bh * TT + row) * 16);
      float s0 = 0, s1 = 0, s2 = 0, s3 = 0;
#pragma unroll
      for (int i = 0; i < 16; i++) {
        float4 qv = q4[i];
        s0 = fmaf(qv.x, kreg[i].x, s0);
        s1 = fmaf(qv.y, kreg[i].y, s1);
        s2 = fmaf(qv.z, kreg[i].z, s2);
        s3 = fmaf(qv.w, kreg[i].w, s3);
      }
      float s = ((s0 + s1) + (s2 + s3)) * QSCALE;
      if (key <= row) {
        float nm = fmaxf(m[rr], s);
        l[rr] = l[rr] * __expf(m[rr] - nm) + __expf(s - nm);
        m[rr] = nm;
      }
    }
  }
  // ---- reduce (m,l) across 64 lanes ----
#pragma unroll
  for (int rr = 0; rr < 16; rr++) {
#pragma unroll
    for (int off = 32; off > 0; off >>= 1) {
      float om = __shfl_xor(m[rr], off);
      float ol = __shfl_xor(l[rr], off);
      float nm = fmaxf(m[rr], om);
      l[rr] = l[rr] * __expf(m[rr] - nm) + ol * __expf(om - nm);
      m[rr] = nm;
    }
    l[rr] = 1.0f / l[rr];   // now holds 1/L
  }
  // ---- sweep 2: recompute scores, accumulate column sums ----
  for (int ci = 0; ci < nch; ci++) {
    __syncthreads();
#pragma unroll
    for (int it = 0; it < 4; it++) {
      int e = tid + it * 256;
      int krow = e >> 4, c4 = e & 15;
      float4 kv = *reinterpret_cast<const float4*>(&K[((size_t)(bh * TT + ci * 64 + krow)) * DD + c4 * 4]);
      Ks4[(krow << 4) + (c4 ^ (krow & 15))] = kv;
    }
    __syncthreads();
    float4 kreg[16];
#pragma unroll
    for (int i = 0; i < 16; i++) kreg[i] = Ks4[(lane << 4) + (i ^ (lane & 15))];
    const int key = ci * 64 + lane;
    float accp = 0.f;
#pragma unroll
    for (int rr = 0; rr < 16; rr++) {
      const int row = qt * 64 + w * 16 + rr;
      const float4* q4 = reinterpret_cast<const float4*>(Q) +
                         __builtin_amdgcn_readfirstlane((bh * TT + row) * 16);
      float s0 = 0, s1 = 0, s2 = 0, s3 = 0;
#pragma unroll
      for (int i = 0; i < 16; i++) {
        float4 qv = q4[i];
        s0 = fmaf(qv.x, kreg[i].x, s0);
        s1 = fmaf(qv.y, kreg[i].y, s1);
        s2 = fmaf(qv.z, kreg[i].z, s2);
        s3 = fmaf(qv.w, kreg[i].w, s3);
      }
      float s = ((s0 + s1) + (s2 + s3)) * QSCALE;
      if (key <= row) accp += __expf(s - m[rr]) * l[rr];
    }
    cs[w][ci * 64 + lane] += accp;
  }
  __syncthreads();
  for (int e = tid; e < 2048; e += 256)
    part[((size_t)(bh * 32 + qt)) * 2048 + e] = ((cs[0][e] + cs[1][e]) + (cs[2][e] + cs[3][e]));
}

// ---------------- Top-K select (exact, tie -> smallest index) + gather ----------------
__global__ __launch_bounds__(256) void topk_gather_kernel(
    const float* __restrict__ part, const float* __restrict__ K, const float* __restrict__ V,
    float* __restrict__ Kk, float* __restrict__ Vk)
{
  const int bh = blockIdx.x, tid = threadIdx.x;
  __shared__ float vals[2048];
  __shared__ int cnts[256];
  __shared__ int sh_tot;
  __shared__ int idxb[KKEEP];
  // fixed-order reduction of partial colsums (deterministic)
  for (int e = tid; e < 2048; e += 256) {
    float s = 0.f;
    for (int qtb = 0; qtb < 32; qtb++) s += part[((size_t)(bh * 32 + qtb)) * 2048 + e];
    vals[e] = (e >= TT - REC) ? 3.0e3f : s;   // forced tokens: sentinel > any colsum (<=2048)
  }
  __syncthreads();
  // binary search for the K-th largest value (positive floats: uint order = float order)
  unsigned lo = 0u, hi = 0x7f800000u;
  for (int it = 0; it < 31; it++) {
    unsigned mid = lo + ((hi - lo + 1) >> 1);
    int c = 0;
    for (int e = tid; e < 2048; e += 256) c += (__float_as_uint(vals[e]) >= mid) ? 1 : 0;
    cnts[tid] = c; __syncthreads();
    if (tid == 0) { int t = 0; for (int i = 0; i < 256; i++) t += cnts[i]; sh_tot = t; }
    __syncthreads();
    if (sh_tot >= KKEEP) lo = mid; else hi = mid - 1;
    __syncthreads();
  }
  const unsigned vstar = lo;
  // strictly-greater emission (order-free set), then ties by ascending index
  int c = 0;
  for (int e = tid; e < 2048; e += 256) c += (__float_as_uint(vals[e]) > vstar) ? 1 : 0;
  cnts[tid] = c; __syncthreads();
  if (tid == 0) {
    int run = 0;
    for (int i = 0; i < 256; i++) { int t = cnts[i]; cnts[i] = run; run += t; }
    sh_tot = run;
  }
  __syncthreads();
  int off = cnts[tid];
  for (int e = tid; e < 2048; e += 256)
    if (__float_as_uint(vals[e]) > vstar) idxb[off++] = e;
  __syncthreads();
  if (tid == 0) {
    int taken = sh_tot;
    for (int i = 0; i < 2048 && taken < KKEEP; i++)
      if (__float_as_uint(vals[i]) == vstar) idxb[taken++] = i;
  }
  __syncthreads();
  // gather pruned K/V
  for (int f = tid; f < KKEEP * DD; f += 256) {
    int kk = f >> 6, d = f & 63;
    int srow = idxb[kk];
    Kk[(size_t)(bh * KKEEP + kk) * DD + d] = K[((size_t)bh * TT + srow) * DD + d];
    Vk[(size_t)(bh * KKEEP + kk) * DD + d] = V[((size_t)bh * TT + srow) * DD + d];
  }
}

// ---------------- Pass-2 attention over pruned keys (no causal mask) ----------------
// grid (qt=64 tiles of 32 rows, bh=32); block 256 = 4 waves x 8 rows.
__global__ __launch_bounds__(256) void attn2_kernel(
    const float* __restrict__ Q, const float* __restrict__ Kk, const float* __restrict__ Vk,
    float* __restrict__ AO)
{
  const int qt = blockIdx.x, bh = blockIdx.y;
  const int tid = threadIdx.x, w = tid >> 6, lane = tid & 63;
  __shared__ float4 Ks4[64 * 16];
  __shared__ float Vs[64 * 65];
  __shared__ float pbuf[4][8][64];

  float sreg[8][7];

  // Phase A: scores (lane = key within chunk)
#pragma unroll
  for (int ci = 0; ci < 7; ci++) {
    if (ci) __syncthreads();
#pragma unroll
    for (int it = 0; it < 4; it++) {
      int e = tid + it * 256;
      int krow = e >> 4, c4 = e & 15;
      int key = ci * 64 + krow;
      float4 kv;
      if (key < KKEEP) kv = *reinterpret_cast<const float4*>(&Kk[((size_t)(bh * KKEEP + key)) * DD + c4 * 4]);
      else kv = make_float4(0.f, 0.f, 0.f, 0.f);
      Ks4[(krow << 4) + (c4 ^ (krow & 15))] = kv;
    }
    __syncthreads();
    float4 kreg[16];
#pragma unroll
    for (int i = 0; i < 16; i++) kreg[i] = Ks4[(lane << 4) + (i ^ (lane & 15))];
    const int key = ci * 64 + lane;
#pragma unroll
    for (int rr = 0; rr < 8; rr++) {
      const int row = qt * 32 + w * 8 + rr;
      const float4* q4 = reinterpret_cast<const float4*>(Q) +
                         __builtin_amdgcn_readfirstlane((bh * TT + row) * 16);
      float s0 = 0, s1 = 0, s2 = 0, s3 = 0;
#pragma unroll
      for (int i = 0; i < 16; i++) {
        float4 qv = q4[i];
        s0 = fmaf(qv.x, kreg[i].x, s0);
        s1 = fmaf(qv.y, kreg[i].y, s1);
        s2 = fmaf(qv.z, kreg[i].z, s2);
        s3 = fmaf(qv.w, kreg[i].w, s3);
      }
      float s = ((s0 + s1) + (s2 + s3)) * QSCALE;
      if (key >= KKEEP) s = -3.0e38f;
      sreg[rr][ci] = s;
    }
  }
  __syncthreads();

  // Phase B: in-register softmax per row (lane-distributed keys)
#pragma unroll
  for (int rr = 0; rr < 8; rr++) {
    float mx = sreg[rr][0];
#pragma unroll
    for (int ci = 1; ci < 7; ci++) mx = fmaxf(mx, sreg[rr][ci]);
#pragma unroll
    for (int off = 32; off > 0; off >>= 1) mx = fmaxf(mx, __shfl_xor(mx, off));
    float sum = 0.f;
#pragma unroll
    for (int ci = 0; ci < 7; ci++) { float p = __expf(sreg[rr][ci] - mx); sreg[rr][ci] = p; sum += p; }
#pragma unroll
    for (int off = 32; off > 0; off >>= 1) sum += __shfl_xor(sum, off);
    float inv = 1.0f / sum;
#pragma unroll
    for (int ci = 0; ci < 7; ci++) sreg[rr][ci] *= inv;
  }

  // Phase C: PV accumulate (lane = output dim d)
  float outr[8];
#pragma unroll
  for (int rr = 0; rr < 8; rr++) outr[rr] = 0.f;
#pragma unroll
  for (int ci = 0; ci < 7; ci++) {
    __syncthreads();
#pragma unroll
    for (int it = 0; it < 16; it++) {
      int e = tid + it * 256;
      int vrow = e >> 6, d = e & 63;
      int key = ci * 64 + vrow;
      Vs[vrow * 65 + d] = (key < KKEEP) ? Vk[((size_t)(bh * KKEEP + key)) * DD + d] : 0.f;
    }
    __syncthreads();
#pragma unroll
    for (int rr = 0; rr < 8; rr++) pbuf[w][rr][lane] = sreg[rr][ci];
#pragma unroll
    for (int half = 0; half < 2; half++) {
      float vreg[32];
#pragma unroll
      for (int j = 0; j < 32; j++) vreg[j] = Vs[(half * 32 + j) * 65 + lane];
#pragma unroll
      for (int rr = 0; rr < 8; rr++) {
        const float4* pb = reinterpret_cast<const float4*>(&pbuf[w][rr][half * 32]);
#pragma unroll
        for (int j4 = 0; j4 < 8; j4++) {
          float4 pv = pb[j4];
          outr[rr] = fmaf(pv.x, vreg[j4 * 4 + 0], outr[rr]);
          outr[rr] = fmaf(pv.y, vreg[j4 * 4 + 1], outr[rr]);
          outr[rr] = fmaf(pv.z, vreg[j4 * 4 + 2], outr[rr]);
          outr[rr] = fmaf(pv.w, vreg[j4 * 4 + 3], outr[rr]);
        }
      }
    }
  }
  const int b = bh >> 4, h = bh & 15;
#pragma unroll
  for (int rr = 0; rr < 8; rr++) {
    int row = qt * 32 + w * 8 + rr;
    AO[((size_t)(b * TT + row)) * EE + h * DD + lane] = outr[rr];
  }
}

extern "C" void kernel_launch(void* const* d_in, const int* in_sizes, int n_in,
                              void* d_out, int out_size, void* d_ws, size_t ws_size,
                              hipStream_t stream)
{
  const float* x     = (const float*)d_in[0];
  const float* Wattn = (const float*)d_in[1];
  const float* Wproj = (const float*)d_in[2];
  float* out = (float*)d_out;
  float* ws  = (float*)d_ws;

  const size_t SZQ = (size_t)NBH * TT * DD;        // 4,194,304
  float* Qb   = ws;
  float* Kb   = Qb + SZQ;
  float* Vb   = Kb + SZQ;
  float* AO   = Vb + SZQ;                          // [B,T,E] = 4,194,304
  float* part = AO + (size_t)2 * TT * EE;          // 2,097,152
  float* Kkp  = part + (size_t)NBH * 32 * TT;      // 800,768
  float* Vkp  = Kkp + (size_t)NBH * KKEEP * DD;    // 800,768
  const size_t need = (size_t)(Vkp - ws) + (size_t)NBH * KKEEP * DD;
  if (ws_size < need * sizeof(float)) return;      // ~82 MB required

  // 1) QKV projection, scattered to head-major Q/K/V
  gemm_nt_f32<<<dim3(24, 32), 256, 0, stream>>>(x, Wattn, nullptr, Qb, Kb, Vb, 4096, 3072, 1024, 1);
  // 2) causal attention column means (partial colsums)
  importance_kernel<<<dim3(32, NBH), 256, 0, stream>>>(Qb, Kb, part);
  // 3) exact top-391 select + K/V gather
  topk_gather_kernel<<<NBH, 256, 0, stream>>>(part, Kb, Vb, Kkp, Vkp);
  // 4) pruned-key attention
  attn2_kernel<<<dim3(64, NBH), 256, 0, stream>>>(Qb, Kkp, Vkp, AO);
  // 5) output projection
  gemm_nt_f32<<<dim3(8, 32), 256, 0, stream>>>(AO, Wproj, out, nullptr, nullptr, nullptr, 4096, 1024, 1024, 0);
}

// Round 2
// 1042.812 us; speedup vs baseline: 6.0972x; 6.0972x over previous
//
#include <hip/hip_runtime.h>
#include <hip/hip_bf16.h>

// PrunedKVAttention: B=2,T=2048,E=1024,H=16,D=64,K_KEEP=391,RECENCY=64
// Round 2: all-f32, GEMM-style register tiling everywhere, no spills, no
// uniform-load latency chains. Deterministic (no atomics).

#define TT 2048
#define EE 1024
#define HH 16
#define DD 64
#define KKEEP 391
#define REC 64
#define NBH 32
#define QSCALE 0.125f
#define KPAD 448   // padded pruned-key count (7 chunks of 64)

// ---------------- GEMM (NT): C[M,N] = A[M,Kd] * B[N,Kd]^T ----------------
// mode 0: plain C write. mode 1: scatter into Q/K/V [bh][t][d] layouts.
__global__ __launch_bounds__(256) void gemm_nt_f32(
    const float* __restrict__ A, const float* __restrict__ Bw,
    float* __restrict__ Cc, float* __restrict__ Qo, float* __restrict__ Ko,
    float* __restrict__ Vo, int M, int N, int Kd, int mode)
{
  __shared__ float As[16][132];
  __shared__ float Bs[16][132];
  const int tid = threadIdx.x;
  const int m0 = blockIdx.y * 128, n0 = blockIdx.x * 128;
  const int tx = tid & 15, ty = tid >> 4;
  float acc[8][8];
#pragma unroll
  for (int i = 0; i < 8; i++)
#pragma unroll
    for (int j = 0; j < 8; j++) acc[i][j] = 0.f;

  for (int k0 = 0; k0 < Kd; k0 += 16) {
    __syncthreads();
#pragma unroll
    for (int it = 0; it < 2; it++) {
      int idx = it * 256 + tid;
      int r = idx >> 2, c4 = idx & 3;
      float4 av = *reinterpret_cast<const float4*>(&A[(size_t)(m0 + r) * Kd + k0 + c4 * 4]);
      As[c4 * 4 + 0][r] = av.x; As[c4 * 4 + 1][r] = av.y;
      As[c4 * 4 + 2][r] = av.z; As[c4 * 4 + 3][r] = av.w;
      float4 bv = *reinterpret_cast<const float4*>(&Bw[(size_t)(n0 + r) * Kd + k0 + c4 * 4]);
      Bs[c4 * 4 + 0][r] = bv.x; Bs[c4 * 4 + 1][r] = bv.y;
      Bs[c4 * 4 + 2][r] = bv.z; Bs[c4 * 4 + 3][r] = bv.w;
    }
    __syncthreads();
#pragma unroll
    for (int kk = 0; kk < 16; kk++) {
      float4 a0 = *reinterpret_cast<const float4*>(&As[kk][ty * 8]);
      float4 a1 = *reinterpret_cast<const float4*>(&As[kk][ty * 8 + 4]);
      float4 b0 = *reinterpret_cast<const float4*>(&Bs[kk][tx * 8]);
      float4 b1 = *reinterpret_cast<const float4*>(&Bs[kk][tx * 8 + 4]);
      float av[8] = {a0.x, a0.y, a0.z, a0.w, a1.x, a1.y, a1.z, a1.w};
      float bv[8] = {b0.x, b0.y, b0.z, b0.w, b1.x, b1.y, b1.z, b1.w};
#pragma unroll
      for (int i = 0; i < 8; i++)
#pragma unroll
        for (int j = 0; j < 8; j++)
          acc[i][j] = fmaf(av[i], bv[j], acc[i][j]);
    }
  }
  if (mode == 0) {
#pragma unroll
    for (int i = 0; i < 8; i++) {
      size_t base = (size_t)(m0 + ty * 8 + i) * N + n0 + tx * 8;
      *reinterpret_cast<float4*>(&Cc[base]) = make_float4(acc[i][0], acc[i][1], acc[i][2], acc[i][3]);
      *reinterpret_cast<float4*>(&Cc[base + 4]) = make_float4(acc[i][4], acc[i][5], acc[i][6], acc[i][7]);
    }
  } else {
    int n = n0 + tx * 8;
    int p = n >> 10, r = n & 1023;
    int h = r >> 6, d0 = r & 63;
    float* dst = (p == 0) ? Qo : (p == 1) ? Ko : Vo;
#pragma unroll
    for (int i = 0; i < 8; i++) {
      int m = m0 + ty * 8 + i;
      int b = m >> 11, t = m & 2047;
      size_t base = ((size_t)((b * HH + h) * TT + t)) * DD + d0;
      *reinterpret_cast<float4*>(&dst[base]) = make_float4(acc[i][0], acc[i][1], acc[i][2], acc[i][3]);
      *reinterpret_cast<float4*>(&dst[base + 4]) = make_float4(acc[i][4], acc[i][5], acc[i][6], acc[i][7]);
    }
  }
}

// ---------------- Importance: causal softmax column sums ----------------
// grid (8 pairs, 32 bh), 512 threads. Block handles row-tiles rt=pair and
// 15-pair (balanced: 17 chunk-units each). k-major XOR-swizzled LDS tiles.
// part[bh][pair][2048]: first-touch write then accumulate (deterministic).
__global__ __launch_bounds__(512) void importance2_kernel(
    const float* __restrict__ Q, const float* __restrict__ K, float* __restrict__ part)
{
  const int pairid = blockIdx.x, bh = blockIdx.y;
  const int tid = threadIdx.x;
  const int tx = tid & 31;        // keys tx*4 .. +3
  const int ty = tid >> 5;        // rows ty*8 .. +7
  const int w  = tid >> 6;        // wave 0..7
  __shared__ float4 Qs[64 * 32];  // [kk][row-block ^ swz], 32 KB
  __shared__ float4 Ks[64 * 32];  // [kk][key-block ^ swz], 32 KB
  float* cswf = (float*)Ks;       // aliased col-sum buffer [8][128] (barrier-fenced)

  for (int half = 0; half < 2; half++) {
    const int rt = half ? (15 - pairid) : pairid;
    const int row0 = rt * 128;
    __syncthreads();
    // stage Q tile (128 rows x 64 dims), k-major swizzled
#pragma unroll
    for (int it = 0; it < 4; it++) {
      int idx = it * 512 + tid;
      int r = idx >> 4, c4 = idx & 15;
      float4 v = *reinterpret_cast<const float4*>(&Q[((size_t)(bh * TT + row0 + r)) * DD + c4 * 4]);
      const float* sv = (const float*)&v;
#pragma unroll
      for (int j = 0; j < 4; j++) {
        int kk = c4 * 4 + j;
        ((float*)&Qs[kk * 32 + ((r >> 2) ^ ((kk >> 2) & 7))])[r & 3] = sv[j];
      }
    }
    const int nch = rt + 1;
    float rsum[8];
#pragma unroll
    for (int i = 0; i < 8; i++) rsum[i] = 0.f;
    float invl[8];
#pragma unroll
    for (int i = 0; i < 8; i++) invl[i] = 0.f;

    for (int sweep = 0; sweep < 2; sweep++) {
      for (int ci = 0; ci < nch; ci++) {
        __syncthreads();
        // stage K chunk (128 keys x 64 dims), k-major swizzled
#pragma unroll
        for (int it = 0; it < 4; it++) {
          int idx = it * 512 + tid;
          int r = idx >> 4, c4 = idx & 15;
          float4 v = *reinterpret_cast<const float4*>(&K[((size_t)(bh * TT + ci * 128 + r)) * DD + c4 * 4]);
          const float* sv = (const float*)&v;
#pragma unroll
          for (int j = 0; j < 4; j++) {
            int kk = c4 * 4 + j;
            ((float*)&Ks[kk * 32 + ((r >> 2) ^ ((kk >> 2) & 7))])[r & 3] = sv[j];
          }
        }
        __syncthreads();
        float acc[8][4];
#pragma unroll
        for (int i = 0; i < 8; i++)
#pragma unroll
          for (int j = 0; j < 4; j++) acc[i][j] = 0.f;
#pragma unroll 8
        for (int kk = 0; kk < 64; kk++) {
          const int e = (kk >> 2) & 7;
          float4 a0 = Qs[kk * 32 + ((2 * ty) ^ e)];
          float4 a1 = Qs[kk * 32 + ((2 * ty + 1) ^ e)];
          float4 b  = Ks[kk * 32 + (tx ^ e)];
          float av[8] = {a0.x, a0.y, a0.z, a0.w, a1.x, a1.y, a1.z, a1.w};
          float bv[4] = {b.x, b.y, b.z, b.w};
#pragma unroll
          for (int i = 0; i < 8; i++)
#pragma unroll
            for (int j = 0; j < 4; j++)
              acc[i][j] = fmaf(av[i], bv[j], acc[i][j]);
        }
        const bool diag = (ci == rt);
        if (sweep == 0) {
#pragma unroll
          for (int i = 0; i < 8; i++)
#pragma unroll
            for (int j = 0; j < 4; j++) {
              float p = __expf(acc[i][j] * QSCALE);
              if (diag && (ci * 128 + tx * 4 + j > row0 + ty * 8 + i)) p = 0.f;
              rsum[i] += p;
            }
        } else {
          float ps[4] = {0.f, 0.f, 0.f, 0.f};
#pragma unroll
          for (int i = 0; i < 8; i++)
#pragma unroll
            for (int j = 0; j < 4; j++) {
              float p = __expf(acc[i][j] * QSCALE) * invl[i];
              if (diag && (ci * 128 + tx * 4 + j > row0 + ty * 8 + i)) p = 0.f;
              ps[j] += p;
            }
#pragma unroll
          for (int j = 0; j < 4; j++) ps[j] += __shfl_xor(ps[j], 32);
          __syncthreads();            // all Ks reads done -> safe to alias as csw
          if ((tid & 32) == 0) {
#pragma unroll
            for (int j = 0; j < 4; j++) cswf[w * 128 + tx * 4 + j] = ps[j];
          }
          __syncthreads();
          if (tid < 128) {
            float s = 0.f;
#pragma unroll
            for (int ww = 0; ww < 8; ww++) s += cswf[ww * 128 + tid];
            size_t pi = ((size_t)(bh * 8 + pairid)) * 2048 + ci * 128 + tid;
            bool wr = (half == 0) || (ci > pairid);   // first touch of this column
            part[pi] = wr ? s : (part[pi] + s);
          }
        }
      }
      if (sweep == 0) {
#pragma unroll
        for (int i = 0; i < 8; i++) {
          float r_ = rsum[i];
#pragma unroll
          for (int off = 1; off <= 16; off <<= 1) r_ += __shfl_xor(r_, off);
          invl[i] = 1.f / r_;
        }
      }
    }
  }
}

// ---------------- Top-K select (exact, ties -> smallest index) + gather ----------------
__global__ __launch_bounds__(256) void topk_gather_kernel(
    const float* __restrict__ part, const float* __restrict__ K, const float* __restrict__ V,
    float* __restrict__ Kk, float* __restrict__ Vk)
{
  const int bh = blockIdx.x, tid = threadIdx.x;
  const int lane = tid & 63, w = tid >> 6;
  __shared__ int redi[4];
  __shared__ int stot;
  __shared__ int base[256];
  __shared__ int idxb[KKEEP];
  unsigned u[8];
#pragma unroll
  for (int k = 0; k < 8; k++) {
    int e = tid * 8 + k;
    float s = 0.f;
#pragma unroll
    for (int p = 0; p < 8; p++)
      if (e < (16 - p) * 128) s += part[((size_t)(bh * 8 + p)) * 2048 + e];
    float v = (e >= TT - REC) ? 3.0e3f : s;   // forced tokens beat any colsum (<=2048)
    u[k] = __float_as_uint(v);
  }
  // binary search for K-th largest value (positive floats: uint order = float order)
  unsigned lo = 0u, hi = 0x7f800000u;
  for (int it = 0; it < 31; it++) {
    unsigned mid = lo + ((hi - lo + 1) >> 1);
    int c = 0;
#pragma unroll
    for (int k = 0; k < 8; k++) c += (u[k] >= mid) ? 1 : 0;
#pragma unroll
    for (int off = 1; off <= 32; off <<= 1) c += __shfl_xor(c, off);
    if (lane == 0) redi[w] = c;
    __syncthreads();
    int tot = redi[0] + redi[1] + redi[2] + redi[3];
    if (tot >= KKEEP) lo = mid; else hi = mid - 1;
    __syncthreads();
  }
  const unsigned vstar = lo;
  // strictly-greater set (order-free), emitted index-ascending
  int cgt = 0, ceq = 0;
#pragma unroll
  for (int k = 0; k < 8; k++) { cgt += (u[k] > vstar) ? 1 : 0; ceq += (u[k] == vstar) ? 1 : 0; }
  base[tid] = cgt; __syncthreads();
  if (tid == 0) {
    int run = 0;
    for (int i = 0; i < 256; i++) { int t = base[i]; base[i] = run; run += t; }
    stot = run;
  }
  __syncthreads();
  int off1 = base[tid];
#pragma unroll
  for (int k = 0; k < 8; k++)
    if (u[k] > vstar) idxb[off1++] = tid * 8 + k;
  __syncthreads();
  base[tid] = ceq; __syncthreads();
  if (tid == 0) {
    int run = 0;
    for (int i = 0; i < 256; i++) { int t = base[i]; base[i] = run; run += t; }
  }
  __syncthreads();
  int off2 = stot + base[tid];
#pragma unroll
  for (int k = 0; k < 8; k++)
    if (u[k] == vstar) { if (off2 < KKEEP) idxb[off2] = tid * 8 + k; off2++; }
  __syncthreads();
  // gather pruned K/V, zero-padded to KPAD rows
  for (int f = tid; f < KPAD * 16; f += 256) {
    int kk = f >> 4, c4 = f & 15;
    float4 kv = make_float4(0.f, 0.f, 0.f, 0.f), vv = kv;
    if (kk < KKEEP) {
      int sr = idxb[kk];
      kv = *reinterpret_cast<const float4*>(&K[((size_t)(bh * TT + sr)) * DD + c4 * 4]);
      vv = *reinterpret_cast<const float4*>(&V[((size_t)(bh * TT + sr)) * DD + c4 * 4]);
    }
    *reinterpret_cast<float4*>(&Kk[((size_t)(bh * KPAD + kk)) * DD + c4 * 4]) = kv;
    *reinterpret_cast<float4*>(&Vk[((size_t)(bh * KPAD + kk)) * DD + c4 * 4]) = vv;
  }
}

// ---------------- Fused pass-2 attention over pruned keys ----------------
// grid (32 row-tiles of 64, 32 bh), 256 threads, 48KB LDS, 4x4 microtile.
__global__ __launch_bounds__(256) void attn2_kernel(
    const float* __restrict__ Q, const float* __restrict__ Kk, const float* __restrict__ Vk,
    float* __restrict__ AO)
{
  const int rt = blockIdx.x, bh = blockIdx.y;
  const int tid = threadIdx.x;
  const int tx = tid & 15, ty = tid >> 4;
  __shared__ float4 Qs[64 * 16];   // [kk][row-block ^ swz], 16 KB
  __shared__ float4 KVs[64 * 16];  // K (k-major swz) then V (natural) per chunk
  __shared__ float4 Ps[64 * 16];   // [key][row-block ^ swz]
  const int row0 = rt * 64;
  // stage Q tile (64 rows x 64 dims), k-major swizzled
#pragma unroll
  for (int it = 0; it < 4; it++) {
    int idx = it * 256 + tid;
    int r = idx >> 4, c4 = idx & 15;
    float4 v = *reinterpret_cast<const float4*>(&Q[((size_t)(bh * TT + row0 + r)) * DD + c4 * 4]);
    const float* sv = (const float*)&v;
#pragma unroll
    for (int j = 0; j < 4; j++) {
      int kk = c4 * 4 + j;
      ((float*)&Qs[kk * 16 + ((r >> 2) ^ ((kk >> 2) & 7))])[r & 3] = sv[j];
    }
  }
  float o[4][4];
  float rsum[4];
#pragma unroll
  for (int i = 0; i < 4; i++) {
    rsum[i] = 0.f;
#pragma unroll
    for (int j = 0; j < 4; j++) o[i][j] = 0.f;
  }
  for (int ci = 0; ci < 7; ci++) {
    __syncthreads();
    // stage K chunk (64 keys x 64 dims), k-major swizzled
#pragma unroll
    for (int it = 0; it < 4; it++) {
      int idx = it * 256 + tid;
      int r = idx >> 4, c4 = idx & 15;
      float4 v = *reinterpret_cast<const float4*>(&Kk[((size_t)(bh * KPAD + ci * 64 + r)) * DD + c4 * 4]);
      const float* sv = (const float*)&v;
#pragma unroll
      for (int j = 0; j < 4; j++) {
        int kk = c4 * 4 + j;
        ((float*)&KVs[kk * 16 + ((r >> 2) ^ ((kk >> 2) & 7))])[r & 3] = sv[j];
      }
    }
    __syncthreads();
    float acc[4][4];
#pragma unroll
    for (int i = 0; i < 4; i++)
#pragma unroll
      for (int j = 0; j < 4; j++) acc[i][j] = 0.f;
#pragma unroll 8
    for (int kk = 0; kk < 64; kk++) {
      const int e = (kk >> 2) & 7;
      float4 a = Qs[kk * 16 + (ty ^ e)];
      float4 b = KVs[kk * 16 + (tx ^ e)];
      float av[4] = {a.x, a.y, a.z, a.w};
      float bv[4] = {b.x, b.y, b.z, b.w};
#pragma unroll
      for (int i = 0; i < 4; i++)
#pragma unroll
        for (int j = 0; j < 4; j++)
          acc[i][j] = fmaf(av[i], bv[j], acc[i][j]);
    }
    float p[4][4];
#pragma unroll
    for (int i = 0; i < 4; i++)
#pragma unroll
      for (int j = 0; j < 4; j++) {
        float pp = __expf(acc[i][j] * QSCALE);
        if (ci * 64 + tx * 4 + j >= KKEEP) pp = 0.f;
        p[i][j] = pp;
        rsum[i] += pp;
      }
    __syncthreads();   // all K reads done -> KVs reusable for V; Ps writable
    // write P~ (packed float4 over this thread's 4 rows)
#pragma unroll
    for (int j = 0; j < 4; j++) {
      int kk = tx * 4 + j;
      Ps[kk * 16 + (ty ^ ((kk >> 2) & 7))] = make_float4(p[0][j], p[1][j], p[2][j], p[3][j]);
    }
    // stage V chunk (natural k-major layout: key = k-dim)
#pragma unroll
    for (int it = 0; it < 4; it++) {
      int idx = it * 256 + tid;
      int r = idx >> 4, c4 = idx & 15;
      float4 v = *reinterpret_cast<const float4*>(&Vk[((size_t)(bh * KPAD + ci * 64 + r)) * DD + c4 * 4]);
      KVs[r * 16 + c4] = v;
    }
    __syncthreads();
#pragma unroll 8
    for (int kk = 0; kk < 64; kk++) {
      const int e = (kk >> 2) & 7;
      float4 pa = Ps[kk * 16 + (ty ^ e)];
      float4 vv = KVs[kk * 16 + tx];
      float pav[4] = {pa.x, pa.y, pa.z, pa.w};
      float vvv[4] = {vv.x, vv.y, vv.z, vv.w};
#pragma unroll
      for (int i = 0; i < 4; i++)
#pragma unroll
        for (int j = 0; j < 4; j++)
          o[i][j] = fmaf(pav[i], vvv[j], o[i][j]);
    }
  }
  float inv[4];
#pragma unroll
  for (int i = 0; i < 4; i++) {
    float r_ = rsum[i];
#pragma unroll
    for (int off = 1; off <= 8; off <<= 1) r_ += __shfl_xor(r_, off);
    inv[i] = 1.f / r_;
  }
  const int b = bh >> 4, h = bh & 15;
#pragma unroll
  for (int i = 0; i < 4; i++) {
    int row = row0 + ty * 4 + i;
    float4 wv = make_float4(o[i][0] * inv[i], o[i][1] * inv[i], o[i][2] * inv[i], o[i][3] * inv[i]);
    *reinterpret_cast<float4*>(&AO[((size_t)(b * TT + row)) * EE + h * DD + tx * 4]) = wv;
  }
}

extern "C" void kernel_launch(void* const* d_in, const int* in_sizes, int n_in,
                              void* d_out, int out_size, void* d_ws, size_t ws_size,
                              hipStream_t stream)
{
  const float* x     = (const float*)d_in[0];
  const float* Wattn = (const float*)d_in[1];
  const float* Wproj = (const float*)d_in[2];
  float* out = (float*)d_out;
  float* ws  = (float*)d_ws;

  const size_t SZQ = (size_t)NBH * TT * DD;        // 4,194,304
  float* Qb   = ws;
  float* Kb   = Qb + SZQ;
  float* Vb   = Kb + SZQ;
  float* AO   = Vb + SZQ;                          // 4,194,304
  float* part = AO + (size_t)2 * TT * EE;          // 32*8*2048 = 524,288
  float* Kkp  = part + (size_t)NBH * 8 * TT;       // 32*448*64 = 917,504
  float* Vkp  = Kkp + (size_t)NBH * KPAD * DD;
  const size_t need = (size_t)(Vkp - ws) + (size_t)NBH * KPAD * DD;
  if (ws_size < need * sizeof(float)) return;      // ~76.5 MB required

  // 1) QKV projection -> head-major Q/K/V
  gemm_nt_f32<<<dim3(24, 32), 256, 0, stream>>>(x, Wattn, nullptr, Qb, Kb, Vb, 4096, 3072, 1024, 1);
  // 2) causal softmax column sums (partial per pair-block)
  importance2_kernel<<<dim3(8, NBH), 512, 0, stream>>>(Qb, Kb, part);
  // 3) exact top-391 + gather (zero-padded to 448)
  topk_gather_kernel<<<NBH, 256, 0, stream>>>(part, Kb, Vb, Kkp, Vkp);
  // 4) fused pruned-key attention
  attn2_kernel<<<dim3(32, NBH), 256, 0, stream>>>(Qb, Kkp, Vkp, AO);
  // 5) output projection
  gemm_nt_f32<<<dim3(8, 32), 256, 0, stream>>>(AO, Wproj, out, nullptr, nullptr, nullptr, 4096, 1024, 1024, 0);
}

// Round 3
// 594.602 us; speedup vs baseline: 10.6932x; 1.7538x over previous
//
#include <hip/hip_runtime.h>
#include <hip/hip_bf16.h>

// PrunedKVAttention: B=2,T=2048,E=1024,H=16,D=64,K_KEEP=391,RECENCY=64
// Round 3: GEMMs -> MFMA via split-bf16 (hi+lo, 3 MFMA products).
// importance/topk/attn2 unchanged (f32, verified). Deterministic.

#define TT 2048
#define EE 1024
#define HH 16
#define DD 64
#define KKEEP 391
#define REC 64
#define NBH 32
#define QSCALE 0.125f
#define KPAD 448

typedef short bf16x8 __attribute__((ext_vector_type(8)));
typedef float f32x4 __attribute__((ext_vector_type(4)));

static __device__ inline unsigned short bf_rn(float x) {
  unsigned u = __float_as_uint(x);
  unsigned r = u + 0x7fffu + ((u >> 16) & 1u);
  return (unsigned short)(r >> 16);
}

// ---------------- split f32 -> (hi, lo) bf16 planes ----------------
__global__ __launch_bounds__(256) void split_kernel(
    const float* __restrict__ src, unsigned short* __restrict__ ho,
    unsigned short* __restrict__ lo_, int n)
{
  int i = (blockIdx.x * 256 + threadIdx.x) * 4;
  const int stride = gridDim.x * 1024;
  for (; i < n; i += stride) {
    float4 v = *reinterpret_cast<const float4*>(&src[i]);
    ushort4 hh, ll;
    float f;
    hh.x = bf_rn(v.x); f = __uint_as_float((unsigned)hh.x << 16); ll.x = bf_rn(v.x - f);
    hh.y = bf_rn(v.y); f = __uint_as_float((unsigned)hh.y << 16); ll.y = bf_rn(v.y - f);
    hh.z = bf_rn(v.z); f = __uint_as_float((unsigned)hh.z << 16); ll.z = bf_rn(v.z - f);
    hh.w = bf_rn(v.w); f = __uint_as_float((unsigned)hh.w << 16); ll.w = bf_rn(v.w - f);
    *reinterpret_cast<ushort4*>(&ho[i]) = hh;
    *reinterpret_cast<ushort4*>(&lo_[i]) = ll;
  }
}

// ---------------- MFMA GEMM (NT): C[M,N] = A[M,K]*B[N,K]^T ----------------
// A,B given as bf16 hi/lo planes. 128x128 tile, 4 waves (2x2), 16x16x32 MFMA,
// 3 products per fragment pair. BK=32. mode 0: plain C. mode 1: QKV scatter.
__global__ __launch_bounds__(256) void gemm_bf16s_nt(
    const unsigned short* __restrict__ Ah, const unsigned short* __restrict__ Al,
    const unsigned short* __restrict__ Bh, const unsigned short* __restrict__ Bl,
    float* __restrict__ Cc, float* __restrict__ Qo, float* __restrict__ Ko,
    float* __restrict__ Vo, int M, int N, int Kd, int mode)
{
  __shared__ unsigned short Ahs[128 * 32];
  __shared__ unsigned short Als[128 * 32];
  __shared__ unsigned short Bhs[128 * 32];
  __shared__ unsigned short Bls[128 * 32];
  const int tid = threadIdx.x;
  const int m0 = blockIdx.y * 128, n0 = blockIdx.x * 128;
  const int w = tid >> 6, lane = tid & 63;
  const int wm = w >> 1, wn = w & 1;
  const int l15 = lane & 15, l4 = lane >> 4;

  f32x4 acc[4][4] = {};

  for (int k0 = 0; k0 < Kd; k0 += 32) {
    // stage 4 planes: 512 chunks of 8 bf16 each; thread does chunks tid, tid+256
#pragma unroll
    for (int cc = 0; cc < 2; cc++) {
      int c = cc * 256 + tid;
      int r = c >> 2, kb = c & 3;
      int pb = kb ^ ((r >> 1) & 3);
      size_t ga = (size_t)(m0 + r) * Kd + k0 + kb * 8;
      size_t gb = (size_t)(n0 + r) * Kd + k0 + kb * 8;
      int so = r * 32 + pb * 8;
      *reinterpret_cast<bf16x8*>(&Ahs[so]) = *reinterpret_cast<const bf16x8*>(&Ah[ga]);
      *reinterpret_cast<bf16x8*>(&Als[so]) = *reinterpret_cast<const bf16x8*>(&Al[ga]);
      *reinterpret_cast<bf16x8*>(&Bhs[so]) = *reinterpret_cast<const bf16x8*>(&Bh[gb]);
      *reinterpret_cast<bf16x8*>(&Bls[so]) = *reinterpret_cast<const bf16x8*>(&Bl[gb]);
    }
    __syncthreads();
    bf16x8 ah[4], al[4], bh[4], bl[4];
#pragma unroll
    for (int i = 0; i < 4; i++) {
      int ar = wm * 64 + i * 16 + l15;
      int aoff = ar * 32 + ((l4 ^ ((ar >> 1) & 3)) * 8);
      ah[i] = *reinterpret_cast<const bf16x8*>(&Ahs[aoff]);
      al[i] = *reinterpret_cast<const bf16x8*>(&Als[aoff]);
      int br = wn * 64 + i * 16 + l15;
      int boff = br * 32 + ((l4 ^ ((br >> 1) & 3)) * 8);
      bh[i] = *reinterpret_cast<const bf16x8*>(&Bhs[boff]);
      bl[i] = *reinterpret_cast<const bf16x8*>(&Bls[boff]);
    }
#pragma unroll
    for (int i = 0; i < 4; i++)
#pragma unroll
      for (int j = 0; j < 4; j++) {
        acc[i][j] = __builtin_amdgcn_mfma_f32_16x16x32_bf16(ah[i], bh[j], acc[i][j], 0, 0, 0);
        acc[i][j] = __builtin_amdgcn_mfma_f32_16x16x32_bf16(ah[i], bl[j], acc[i][j], 0, 0, 0);
        acc[i][j] = __builtin_amdgcn_mfma_f32_16x16x32_bf16(al[i], bh[j], acc[i][j], 0, 0, 0);
      }
    __syncthreads();
  }

  if (mode == 0) {
#pragma unroll
    for (int i = 0; i < 4; i++) {
      int mrow0 = m0 + wm * 64 + i * 16 + l4 * 4;
#pragma unroll
      for (int j = 0; j < 4; j++) {
        int ncol = n0 + wn * 64 + j * 16 + l15;
#pragma unroll
        for (int r = 0; r < 4; r++)
          Cc[(size_t)(mrow0 + r) * N + ncol] = acc[i][j][r];
      }
    }
  } else {
#pragma unroll
    for (int j = 0; j < 4; j++) {
      int n = n0 + wn * 64 + j * 16 + l15;
      int p = n >> 10, rr = n & 1023;
      int h = rr >> 6, d0 = rr & 63;
      float* dst = (p == 0) ? Qo : (p == 1) ? Ko : Vo;
#pragma unroll
      for (int i = 0; i < 4; i++) {
        int mrow0 = m0 + wm * 64 + i * 16 + l4 * 4;
#pragma unroll
        for (int r = 0; r < 4; r++) {
          int m = mrow0 + r;
          int b = m >> 11, t = m & 2047;
          dst[((size_t)((b * HH + h) * TT + t)) * DD + d0] = acc[i][j][r];
        }
      }
    }
  }
}

// ---------------- Importance: causal softmax column sums ----------------
__global__ __launch_bounds__(512) void importance2_kernel(
    const float* __restrict__ Q, const float* __restrict__ K, float* __restrict__ part)
{
  const int pairid = blockIdx.x, bh = blockIdx.y;
  const int tid = threadIdx.x;
  const int tx = tid & 31;
  const int ty = tid >> 5;
  const int w  = tid >> 6;
  __shared__ float4 Qs[64 * 32];
  __shared__ float4 Ks[64 * 32];
  float* cswf = (float*)Ks;

  for (int half = 0; half < 2; half++) {
    const int rt = half ? (15 - pairid) : pairid;
    const int row0 = rt * 128;
    __syncthreads();
#pragma unroll
    for (int it = 0; it < 4; it++) {
      int idx = it * 512 + tid;
      int r = idx >> 4, c4 = idx & 15;
      float4 v = *reinterpret_cast<const float4*>(&Q[((size_t)(bh * TT + row0 + r)) * DD + c4 * 4]);
      const float* sv = (const float*)&v;
#pragma unroll
      for (int j = 0; j < 4; j++) {
        int kk = c4 * 4 + j;
        ((float*)&Qs[kk * 32 + ((r >> 2) ^ ((kk >> 2) & 7))])[r & 3] = sv[j];
      }
    }
    const int nch = rt + 1;
    float rsum[8];
#pragma unroll
    for (int i = 0; i < 8; i++) rsum[i] = 0.f;
    float invl[8];
#pragma unroll
    for (int i = 0; i < 8; i++) invl[i] = 0.f;

    for (int sweep = 0; sweep < 2; sweep++) {
      for (int ci = 0; ci < nch; ci++) {
        __syncthreads();
#pragma unroll
        for (int it = 0; it < 4; it++) {
          int idx = it * 512 + tid;
          int r = idx >> 4, c4 = idx & 15;
          float4 v = *reinterpret_cast<const float4*>(&K[((size_t)(bh * TT + ci * 128 + r)) * DD + c4 * 4]);
          const float* sv = (const float*)&v;
#pragma unroll
          for (int j = 0; j < 4; j++) {
            int kk = c4 * 4 + j;
            ((float*)&Ks[kk * 32 + ((r >> 2) ^ ((kk >> 2) & 7))])[r & 3] = sv[j];
          }
        }
        __syncthreads();
        float acc[8][4];
#pragma unroll
        for (int i = 0; i < 8; i++)
#pragma unroll
          for (int j = 0; j < 4; j++) acc[i][j] = 0.f;
#pragma unroll 8
        for (int kk = 0; kk < 64; kk++) {
          const int e = (kk >> 2) & 7;
          float4 a0 = Qs[kk * 32 + ((2 * ty) ^ e)];
          float4 a1 = Qs[kk * 32 + ((2 * ty + 1) ^ e)];
          float4 b  = Ks[kk * 32 + (tx ^ e)];
          float av[8] = {a0.x, a0.y, a0.z, a0.w, a1.x, a1.y, a1.z, a1.w};
          float bv[4] = {b.x, b.y, b.z, b.w};
#pragma unroll
          for (int i = 0; i < 8; i++)
#pragma unroll
            for (int j = 0; j < 4; j++)
              acc[i][j] = fmaf(av[i], bv[j], acc[i][j]);
        }
        const bool diag = (ci == rt);
        if (sweep == 0) {
#pragma unroll
          for (int i = 0; i < 8; i++)
#pragma unroll
            for (int j = 0; j < 4; j++) {
              float p = __expf(acc[i][j] * QSCALE);
              if (diag && (ci * 128 + tx * 4 + j > row0 + ty * 8 + i)) p = 0.f;
              rsum[i] += p;
            }
        } else {
          float ps[4] = {0.f, 0.f, 0.f, 0.f};
#pragma unroll
          for (int i = 0; i < 8; i++)
#pragma unroll
            for (int j = 0; j < 4; j++) {
              float p = __expf(acc[i][j] * QSCALE) * invl[i];
              if (diag && (ci * 128 + tx * 4 + j > row0 + ty * 8 + i)) p = 0.f;
              ps[j] += p;
            }
#pragma unroll
          for (int j = 0; j < 4; j++) ps[j] += __shfl_xor(ps[j], 32);
          __syncthreads();
          if ((tid & 32) == 0) {
#pragma unroll
            for (int j = 0; j < 4; j++) cswf[w * 128 + tx * 4 + j] = ps[j];
          }
          __syncthreads();
          if (tid < 128) {
            float s = 0.f;
#pragma unroll
            for (int ww = 0; ww < 8; ww++) s += cswf[ww * 128 + tid];
            size_t pi = ((size_t)(bh * 8 + pairid)) * 2048 + ci * 128 + tid;
            bool wr = (half == 0) || (ci > pairid);
            part[pi] = wr ? s : (part[pi] + s);
          }
        }
      }
      if (sweep == 0) {
#pragma unroll
        for (int i = 0; i < 8; i++) {
          float r_ = rsum[i];
#pragma unroll
          for (int off = 1; off <= 16; off <<= 1) r_ += __shfl_xor(r_, off);
          invl[i] = 1.f / r_;
        }
      }
    }
  }
}

// ---------------- Top-K select (exact, ties -> smallest index) + gather ----------------
__global__ __launch_bounds__(256) void topk_gather_kernel(
    const float* __restrict__ part, const float* __restrict__ K, const float* __restrict__ V,
    float* __restrict__ Kk, float* __restrict__ Vk)
{
  const int bh = blockIdx.x, tid = threadIdx.x;
  const int lane = tid & 63, w = tid >> 6;
  __shared__ int redi[4];
  __shared__ int stot;
  __shared__ int base[256];
  __shared__ int idxb[KKEEP];
  unsigned u[8];
#pragma unroll
  for (int k = 0; k < 8; k++) {
    int e = tid * 8 + k;
    float s = 0.f;
#pragma unroll
    for (int p = 0; p < 8; p++)
      if (e < (16 - p) * 128) s += part[((size_t)(bh * 8 + p)) * 2048 + e];
    float v = (e >= TT - REC) ? 3.0e3f : s;
    u[k] = __float_as_uint(v);
  }
  unsigned lo = 0u, hi = 0x7f800000u;
  for (int it = 0; it < 31; it++) {
    unsigned mid = lo + ((hi - lo + 1) >> 1);
    int c = 0;
#pragma unroll
    for (int k = 0; k < 8; k++) c += (u[k] >= mid) ? 1 : 0;
#pragma unroll
    for (int off = 1; off <= 32; off <<= 1) c += __shfl_xor(c, off);
    if (lane == 0) redi[w] = c;
    __syncthreads();
    int tot = redi[0] + redi[1] + redi[2] + redi[3];
    if (tot >= KKEEP) lo = mid; else hi = mid - 1;
    __syncthreads();
  }
  const unsigned vstar = lo;
  int cgt = 0, ceq = 0;
#pragma unroll
  for (int k = 0; k < 8; k++) { cgt += (u[k] > vstar) ? 1 : 0; ceq += (u[k] == vstar) ? 1 : 0; }
  base[tid] = cgt; __syncthreads();
  if (tid == 0) {
    int run = 0;
    for (int i = 0; i < 256; i++) { int t = base[i]; base[i] = run; run += t; }
    stot = run;
  }
  __syncthreads();
  int off1 = base[tid];
#pragma unroll
  for (int k = 0; k < 8; k++)
    if (u[k] > vstar) idxb[off1++] = tid * 8 + k;
  __syncthreads();
  base[tid] = ceq; __syncthreads();
  if (tid == 0) {
    int run = 0;
    for (int i = 0; i < 256; i++) { int t = base[i]; base[i] = run; run += t; }
  }
  __syncthreads();
  int off2 = stot + base[tid];
#pragma unroll
  for (int k = 0; k < 8; k++)
    if (u[k] == vstar) { if (off2 < KKEEP) idxb[off2] = tid * 8 + k; off2++; }
  __syncthreads();
  for (int f = tid; f < KPAD * 16; f += 256) {
    int kk = f >> 4, c4 = f & 15;
    float4 kv = make_float4(0.f, 0.f, 0.f, 0.f), vv = kv;
    if (kk < KKEEP) {
      int sr = idxb[kk];
      kv = *reinterpret_cast<const float4*>(&K[((size_t)(bh * TT + sr)) * DD + c4 * 4]);
      vv = *reinterpret_cast<const float4*>(&V[((size_t)(bh * TT + sr)) * DD + c4 * 4]);
    }
    *reinterpret_cast<float4*>(&Kk[((size_t)(bh * KPAD + kk)) * DD + c4 * 4]) = kv;
    *reinterpret_cast<float4*>(&Vk[((size_t)(bh * KPAD + kk)) * DD + c4 * 4]) = vv;
  }
}

// ---------------- Fused pass-2 attention over pruned keys ----------------
// Emits split-bf16 AO planes directly (consumed by MFMA proj GEMM).
__global__ __launch_bounds__(256) void attn2_kernel(
    const float* __restrict__ Q, const float* __restrict__ Kk, const float* __restrict__ Vk,
    unsigned short* __restrict__ AOh, unsigned short* __restrict__ AOl)
{
  const int rt = blockIdx.x, bh = blockIdx.y;
  const int tid = threadIdx.x;
  const int tx = tid & 15, ty = tid >> 4;
  __shared__ float4 Qs[64 * 16];
  __shared__ float4 KVs[64 * 16];
  __shared__ float4 Ps[64 * 16];
  const int row0 = rt * 64;
#pragma unroll
  for (int it = 0; it < 4; it++) {
    int idx = it * 256 + tid;
    int r = idx >> 4, c4 = idx & 15;
    float4 v = *reinterpret_cast<const float4*>(&Q[((size_t)(bh * TT + row0 + r)) * DD + c4 * 4]);
    const float* sv = (const float*)&v;
#pragma unroll
    for (int j = 0; j < 4; j++) {
      int kk = c4 * 4 + j;
      ((float*)&Qs[kk * 16 + ((r >> 2) ^ ((kk >> 2) & 7))])[r & 3] = sv[j];
    }
  }
  float o[4][4];
  float rsum[4];
#pragma unroll
  for (int i = 0; i < 4; i++) {
    rsum[i] = 0.f;
#pragma unroll
    for (int j = 0; j < 4; j++) o[i][j] = 0.f;
  }
  for (int ci = 0; ci < 7; ci++) {
    __syncthreads();
#pragma unroll
    for (int it = 0; it < 4; it++) {
      int idx = it * 256 + tid;
      int r = idx >> 4, c4 = idx & 15;
      float4 v = *reinterpret_cast<const float4*>(&Kk[((size_t)(bh * KPAD + ci * 64 + r)) * DD + c4 * 4]);
      const float* sv = (const float*)&v;
#pragma unroll
      for (int j = 0; j < 4; j++) {
        int kk = c4 * 4 + j;
        ((float*)&KVs[kk * 16 + ((r >> 2) ^ ((kk >> 2) & 7))])[r & 3] = sv[j];
      }
    }
    __syncthreads();
    float acc[4][4];
#pragma unroll
    for (int i = 0; i < 4; i++)
#pragma unroll
      for (int j = 0; j < 4; j++) acc[i][j] = 0.f;
#pragma unroll 8
    for (int kk = 0; kk < 64; kk++) {
      const int e = (kk >> 2) & 7;
      float4 a = Qs[kk * 16 + (ty ^ e)];
      float4 b = KVs[kk * 16 + (tx ^ e)];
      float av[4] = {a.x, a.y, a.z, a.w};
      float bv[4] = {b.x, b.y, b.z, b.w};
#pragma unroll
      for (int i = 0; i < 4; i++)
#pragma unroll
        for (int j = 0; j < 4; j++)
          acc[i][j] = fmaf(av[i], bv[j], acc[i][j]);
    }
    float p[4][4];
#pragma unroll
    for (int i = 0; i < 4; i++)
#pragma unroll
      for (int j = 0; j < 4; j++) {
        float pp = __expf(acc[i][j] * QSCALE);
        if (ci * 64 + tx * 4 + j >= KKEEP) pp = 0.f;
        p[i][j] = pp;
        rsum[i] += pp;
      }
    __syncthreads();
#pragma unroll
    for (int j = 0; j < 4; j++) {
      int kk = tx * 4 + j;
      Ps[kk * 16 + (ty ^ ((kk >> 2) & 7))] = make_float4(p[0][j], p[1][j], p[2][j], p[3][j]);
    }
#pragma unroll
    for (int it = 0; it < 4; it++) {
      int idx = it * 256 + tid;
      int r = idx >> 4, c4 = idx & 15;
      float4 v = *reinterpret_cast<const float4*>(&Vk[((size_t)(bh * KPAD + ci * 64 + r)) * DD + c4 * 4]);
      KVs[r * 16 + c4] = v;
    }
    __syncthreads();
#pragma unroll 8
    for (int kk = 0; kk < 64; kk++) {
      const int e = (kk >> 2) & 7;
      float4 pa = Ps[kk * 16 + (ty ^ e)];
      float4 vv = KVs[kk * 16 + tx];
      float pav[4] = {pa.x, pa.y, pa.z, pa.w};
      float vvv[4] = {vv.x, vv.y, vv.z, vv.w};
#pragma unroll
      for (int i = 0; i < 4; i++)
#pragma unroll
        for (int j = 0; j < 4; j++)
          o[i][j] = fmaf(pav[i], vvv[j], o[i][j]);
    }
  }
  float inv[4];
#pragma unroll
  for (int i = 0; i < 4; i++) {
    float r_ = rsum[i];
#pragma unroll
    for (int off = 1; off <= 8; off <<= 1) r_ += __shfl_xor(r_, off);
    inv[i] = 1.f / r_;
  }
  const int b = bh >> 4, h = bh & 15;
#pragma unroll
  for (int i = 0; i < 4; i++) {
    int row = row0 + ty * 4 + i;
    size_t bb = ((size_t)(b * TT + row)) * EE + h * DD + tx * 4;
    ushort4 hh, ll;
    float x, f;
    x = o[i][0] * inv[i]; hh.x = bf_rn(x); f = __uint_as_float((unsigned)hh.x << 16); ll.x = bf_rn(x - f);
    x = o[i][1] * inv[i]; hh.y = bf_rn(x); f = __uint_as_float((unsigned)hh.y << 16); ll.y = bf_rn(x - f);
    x = o[i][2] * inv[i]; hh.z = bf_rn(x); f = __uint_as_float((unsigned)hh.z << 16); ll.z = bf_rn(x - f);
    x = o[i][3] * inv[i]; hh.w = bf_rn(x); f = __uint_as_float((unsigned)hh.w << 16); ll.w = bf_rn(x - f);
    *reinterpret_cast<ushort4*>(&AOh[bb]) = hh;
    *reinterpret_cast<ushort4*>(&AOl[bb]) = ll;
  }
}

extern "C" void kernel_launch(void* const* d_in, const int* in_sizes, int n_in,
                              void* d_out, int out_size, void* d_ws, size_t ws_size,
                              hipStream_t stream)
{
  const float* x     = (const float*)d_in[0];
  const float* Wattn = (const float*)d_in[1];
  const float* Wproj = (const float*)d_in[2];
  float* out = (float*)d_out;
  float* ws  = (float*)d_ws;

  const size_t SZQ = (size_t)NBH * TT * DD;          // 4,194,304 floats
  float* Qb   = ws;
  float* Kb   = Qb + SZQ;
  float* Vb   = Kb + SZQ;
  float* part = Vb + SZQ;                            // 524,288
  float* Kkp  = part + (size_t)NBH * 8 * TT;         // 917,504
  float* Vkp  = Kkp + (size_t)NBH * KPAD * DD;       // 917,504
  unsigned short* S1 = (unsigned short*)(Vkp + (size_t)NBH * KPAD * DD);
  unsigned short* xh = S1;                           // 4096*1024 shorts
  unsigned short* xl = xh + (size_t)4096 * 1024;
  unsigned short* Wh = xl + (size_t)4096 * 1024;     // 3072*1024 shorts
  unsigned short* Wl = Wh + (size_t)3072 * 1024;
  unsigned short* AOh = xh;                          // alias (x splits dead after QKV)
  unsigned short* AOl = xl;
  unsigned short* Ph  = Wh;                          // alias (Wattn splits dead after QKV)
  unsigned short* Pl  = Ph + (size_t)1024 * 1024;

  const size_t needB =
      ((size_t)3 * SZQ + (size_t)NBH * 8 * TT + (size_t)2 * NBH * KPAD * DD) * 4 +
      ((size_t)2 * 4096 * 1024 + (size_t)2 * 3072 * 1024) * 2;   // ~89 MB
  if (ws_size < needB) return;

  // 0) split x, W_attn into bf16 hi/lo planes
  split_kernel<<<512, 256, 0, stream>>>(x, xh, xl, 4096 * 1024);
  split_kernel<<<512, 256, 0, stream>>>(Wattn, Wh, Wl, 3072 * 1024);
  // 1) QKV projection (MFMA) -> head-major Q/K/V (f32)
  gemm_bf16s_nt<<<dim3(24, 32), 256, 0, stream>>>(xh, xl, Wh, Wl, nullptr, Qb, Kb, Vb, 4096, 3072, 1024, 1);
  // 1b) split W_proj (into region aliasing W_attn splits -- after QKV GEMM)
  split_kernel<<<512, 256, 0, stream>>>(Wproj, Ph, Pl, 1024 * 1024);
  // 2) causal softmax column sums
  importance2_kernel<<<dim3(8, NBH), 512, 0, stream>>>(Qb, Kb, part);
  // 3) exact top-391 + gather (zero-padded to 448)
  topk_gather_kernel<<<NBH, 256, 0, stream>>>(part, Kb, Vb, Kkp, Vkp);
  // 4) fused pruned-key attention -> split-bf16 AO planes
  attn2_kernel<<<dim3(32, NBH), 256, 0, stream>>>(Qb, Kkp, Vkp, AOh, AOl);
  // 5) output projection (MFMA)
  gemm_bf16s_nt<<<dim3(8, 32), 256, 0, stream>>>(AOh, AOl, Ph, Pl, out, nullptr, nullptr, nullptr, 4096, 1024, 1024, 0);
}

// Round 4
// 409.965 us; speedup vs baseline: 15.5092x; 1.4504x over previous
//
#include <hip/hip_runtime.h>
#include <hip/hip_bf16.h>

// PrunedKVAttention: B=2,T=2048,E=1024,H=16,D=64,K_KEEP=391,RECENCY=64
// Round 4: importance pass -> MFMA (split-bf16 Q/K emitted by QKV GEMM).
// Workspace layout total unchanged (89,128,960 B). Deterministic.

#define TT 2048
#define EE 1024
#define HH 16
#define DD 64
#define KKEEP 391
#define REC 64
#define NBH 32
#define QSCALE 0.125f
#define KPAD 448

typedef short bf16x8 __attribute__((ext_vector_type(8)));
typedef float f32x4 __attribute__((ext_vector_type(4)));

static __device__ inline unsigned short bf_rn(float x) {
  unsigned u = __float_as_uint(x);
  unsigned r = u + 0x7fffu + ((u >> 16) & 1u);
  return (unsigned short)(r >> 16);
}
static __device__ inline float bf_up(unsigned short h) {
  return __uint_as_float((unsigned)h << 16);
}

// ---------------- split f32 -> (hi, lo) bf16 planes ----------------
__global__ __launch_bounds__(256) void split_kernel(
    const float* __restrict__ src, unsigned short* __restrict__ ho,
    unsigned short* __restrict__ lo_, int n)
{
  int i = (blockIdx.x * 256 + threadIdx.x) * 4;
  const int stride = gridDim.x * 1024;
  for (; i < n; i += stride) {
    float4 v = *reinterpret_cast<const float4*>(&src[i]);
    ushort4 hh, ll;
    float f;
    hh.x = bf_rn(v.x); f = bf_up(hh.x); ll.x = bf_rn(v.x - f);
    hh.y = bf_rn(v.y); f = bf_up(hh.y); ll.y = bf_rn(v.y - f);
    hh.z = bf_rn(v.z); f = bf_up(hh.z); ll.z = bf_rn(v.z - f);
    hh.w = bf_rn(v.w); f = bf_up(hh.w); ll.w = bf_rn(v.w - f);
    *reinterpret_cast<ushort4*>(&ho[i]) = hh;
    *reinterpret_cast<ushort4*>(&lo_[i]) = ll;
  }
}

// ---------------- MFMA GEMM (NT): C[M,N] = A[M,K]*B[N,K]^T ----------------
// mode 0: plain f32 C. mode 1: QKV scatter -> Q,K as split-bf16 planes, V f32.
__global__ __launch_bounds__(256) void gemm_bf16s_nt(
    const unsigned short* __restrict__ Ah, const unsigned short* __restrict__ Al,
    const unsigned short* __restrict__ Bh, const unsigned short* __restrict__ Bl,
    float* __restrict__ Cc, unsigned short* __restrict__ Qho, unsigned short* __restrict__ Qlo,
    unsigned short* __restrict__ Kho, unsigned short* __restrict__ Klo,
    float* __restrict__ Vo, int M, int N, int Kd, int mode)
{
  __shared__ unsigned short Ahs[128 * 32];
  __shared__ unsigned short Als[128 * 32];
  __shared__ unsigned short Bhs[128 * 32];
  __shared__ unsigned short Bls[128 * 32];
  const int tid = threadIdx.x;
  const int m0 = blockIdx.y * 128, n0 = blockIdx.x * 128;
  const int w = tid >> 6, lane = tid & 63;
  const int wm = w >> 1, wn = w & 1;
  const int l15 = lane & 15, l4 = lane >> 4;

  f32x4 acc[4][4] = {};

  for (int k0 = 0; k0 < Kd; k0 += 32) {
#pragma unroll
    for (int cc = 0; cc < 2; cc++) {
      int c = cc * 256 + tid;
      int r = c >> 2, kb = c & 3;
      int pb = kb ^ ((r >> 1) & 3);
      size_t ga = (size_t)(m0 + r) * Kd + k0 + kb * 8;
      size_t gb = (size_t)(n0 + r) * Kd + k0 + kb * 8;
      int so = r * 32 + pb * 8;
      *reinterpret_cast<bf16x8*>(&Ahs[so]) = *reinterpret_cast<const bf16x8*>(&Ah[ga]);
      *reinterpret_cast<bf16x8*>(&Als[so]) = *reinterpret_cast<const bf16x8*>(&Al[ga]);
      *reinterpret_cast<bf16x8*>(&Bhs[so]) = *reinterpret_cast<const bf16x8*>(&Bh[gb]);
      *reinterpret_cast<bf16x8*>(&Bls[so]) = *reinterpret_cast<const bf16x8*>(&Bl[gb]);
    }
    __syncthreads();
    bf16x8 ah[4], al[4], bh[4], bl[4];
#pragma unroll
    for (int i = 0; i < 4; i++) {
      int ar = wm * 64 + i * 16 + l15;
      int aoff = ar * 32 + ((l4 ^ ((ar >> 1) & 3)) * 8);
      ah[i] = *reinterpret_cast<const bf16x8*>(&Ahs[aoff]);
      al[i] = *reinterpret_cast<const bf16x8*>(&Als[aoff]);
      int br = wn * 64 + i * 16 + l15;
      int boff = br * 32 + ((l4 ^ ((br >> 1) & 3)) * 8);
      bh[i] = *reinterpret_cast<const bf16x8*>(&Bhs[boff]);
      bl[i] = *reinterpret_cast<const bf16x8*>(&Bls[boff]);
    }
#pragma unroll
    for (int i = 0; i < 4; i++)
#pragma unroll
      for (int j = 0; j < 4; j++) {
        acc[i][j] = __builtin_amdgcn_mfma_f32_16x16x32_bf16(ah[i], bh[j], acc[i][j], 0, 0, 0);
        acc[i][j] = __builtin_amdgcn_mfma_f32_16x16x32_bf16(ah[i], bl[j], acc[i][j], 0, 0, 0);
        acc[i][j] = __builtin_amdgcn_mfma_f32_16x16x32_bf16(al[i], bh[j], acc[i][j], 0, 0, 0);
      }
    __syncthreads();
  }

  if (mode == 0) {
#pragma unroll
    for (int i = 0; i < 4; i++) {
      int mrow0 = m0 + wm * 64 + i * 16 + l4 * 4;
#pragma unroll
      for (int j = 0; j < 4; j++) {
        int ncol = n0 + wn * 64 + j * 16 + l15;
#pragma unroll
        for (int r = 0; r < 4; r++)
          Cc[(size_t)(mrow0 + r) * N + ncol] = acc[i][j][r];
      }
    }
  } else {
#pragma unroll
    for (int j = 0; j < 4; j++) {
      int n = n0 + wn * 64 + j * 16 + l15;
      int p = n >> 10, rr = n & 1023;
      int h = rr >> 6, d0 = rr & 63;
#pragma unroll
      for (int i = 0; i < 4; i++) {
        int mrow0 = m0 + wm * 64 + i * 16 + l4 * 4;
#pragma unroll
        for (int r = 0; r < 4; r++) {
          int m = mrow0 + r;
          int b = m >> 11, t = m & 2047;
          size_t idx = ((size_t)((b * HH + h) * TT + t)) * DD + d0;
          float v = acc[i][j][r];
          if (p == 2) {
            Vo[idx] = v;
          } else {
            unsigned short hi_ = bf_rn(v);
            unsigned short lo2 = bf_rn(v - bf_up(hi_));
            if (p == 0) { Qho[idx] = hi_; Qlo[idx] = lo2; }
            else        { Kho[idx] = hi_; Klo[idx] = lo2; }
          }
        }
      }
    }
  }
}

// ---------------- Importance (MFMA): causal softmax column sums ----------------
// grid (8 pairs, 32 bh), 512 thr = 8 waves (4 row x 2 col). Per half: 128 rows.
// Chunks of 128 keys; 16x16x32 bf16 MFMA x3 (split). part[bh][pair][2048].
__global__ __launch_bounds__(512) void importance3_kernel(
    const unsigned short* __restrict__ Qh, const unsigned short* __restrict__ Ql,
    const unsigned short* __restrict__ Kh, const unsigned short* __restrict__ Kl,
    float* __restrict__ part)
{
  const int pairid = blockIdx.x, bh = blockIdx.y;
  const int tid = threadIdx.x;
  const int w = tid >> 6, lane = tid & 63;
  const int wm = w >> 1, wn = w & 1;
  const int l15 = lane & 15, l4 = lane >> 4;
  __shared__ unsigned short Qhs[128 * 64];   // 16 KB each
  __shared__ unsigned short Qls[128 * 64];
  __shared__ unsigned short Khs[128 * 64];
  __shared__ unsigned short Kls[128 * 64];
  float* csw = (float*)Khs;   // [8][128] col-sum slab (barrier-fenced alias)
  float* rsb = (float*)Kls;   // [2][128] row-sum exchange (barrier-fenced alias)

  for (int half = 0; half < 2; half++) {
    const int rt = half ? (15 - pairid) : pairid;
    const int row0 = rt * 128;
    const int nch = rt + 1;
    __syncthreads();
    // stage Q tile (128 rows x 64 dims), swizzled chunk layout
#pragma unroll
    for (int cc = 0; cc < 2; cc++) {
      int c = cc * 512 + tid;
      int r = c >> 3, k8 = c & 7;
      int so = r * 64 + ((k8 ^ (r & 7)) * 8);
      size_t ga = ((size_t)(bh * TT + row0 + r)) * DD + k8 * 8;
      *reinterpret_cast<bf16x8*>(&Qhs[so]) = *reinterpret_cast<const bf16x8*>(&Qh[ga]);
      *reinterpret_cast<bf16x8*>(&Qls[so]) = *reinterpret_cast<const bf16x8*>(&Ql[ga]);
    }

    float rsum[2][4];
#pragma unroll
    for (int i = 0; i < 2; i++)
#pragma unroll
      for (int r = 0; r < 4; r++) rsum[i][r] = 0.f;
    float invl[2][4];

    // ================= sweep 1: row sums =================
    for (int ci = 0; ci < nch; ci++) {
      __syncthreads();
#pragma unroll
      for (int cc = 0; cc < 2; cc++) {
        int c = cc * 512 + tid;
        int r = c >> 3, k8 = c & 7;
        int so = r * 64 + ((k8 ^ (r & 7)) * 8);
        size_t ga = ((size_t)(bh * TT + ci * 128 + r)) * DD + k8 * 8;
        *reinterpret_cast<bf16x8*>(&Khs[so]) = *reinterpret_cast<const bf16x8*>(&Kh[ga]);
        *reinterpret_cast<bf16x8*>(&Kls[so]) = *reinterpret_cast<const bf16x8*>(&Kl[ga]);
      }
      __syncthreads();
      f32x4 acc[2][4] = {};
#pragma unroll
      for (int ks = 0; ks < 2; ks++) {
        bf16x8 ah[2], al_[2];
#pragma unroll
        for (int i = 0; i < 2; i++) {
          int ar = wm * 32 + i * 16 + l15;
          int off = ar * 64 + (((ks * 4 + l4) ^ (ar & 7)) * 8);
          ah[i]  = *reinterpret_cast<const bf16x8*>(&Qhs[off]);
          al_[i] = *reinterpret_cast<const bf16x8*>(&Qls[off]);
        }
#pragma unroll
        for (int j = 0; j < 4; j++) {
          int br = wn * 64 + j * 16 + l15;
          int off = br * 64 + (((ks * 4 + l4) ^ (br & 7)) * 8);
          bf16x8 bh_ = *reinterpret_cast<const bf16x8*>(&Khs[off]);
          bf16x8 bl_ = *reinterpret_cast<const bf16x8*>(&Kls[off]);
#pragma unroll
          for (int i = 0; i < 2; i++) {
            acc[i][j] = __builtin_amdgcn_mfma_f32_16x16x32_bf16(ah[i], bh_, acc[i][j], 0, 0, 0);
            acc[i][j] = __builtin_amdgcn_mfma_f32_16x16x32_bf16(ah[i], bl_, acc[i][j], 0, 0, 0);
            acc[i][j] = __builtin_amdgcn_mfma_f32_16x16x32_bf16(al_[i], bh_, acc[i][j], 0, 0, 0);
          }
        }
      }
      const bool diag = (ci == rt);
#pragma unroll
      for (int i = 0; i < 2; i++)
#pragma unroll
        for (int r = 0; r < 4; r++) {
          int row = row0 + wm * 32 + i * 16 + l4 * 4 + r;
          float s = 0.f;
#pragma unroll
          for (int j = 0; j < 4; j++) {
            int key = ci * 128 + wn * 64 + j * 16 + l15;
            float p = __expf(acc[i][j][r] * QSCALE);
            if (diag && key > row) p = 0.f;
            s += p;
          }
          rsum[i][r] += s;
        }
    }
    // reduce rowsums: over 16 cols (l15 lanes), then across wn pair via LDS
#pragma unroll
    for (int i = 0; i < 2; i++)
#pragma unroll
      for (int r = 0; r < 4; r++) {
        float v = rsum[i][r];
        v += __shfl_xor(v, 1); v += __shfl_xor(v, 2);
        v += __shfl_xor(v, 4); v += __shfl_xor(v, 8);
        rsum[i][r] = v;
      }
    __syncthreads();   // last chunk's K frag reads done -> safe to alias Kls
    if (l15 == 0) {
#pragma unroll
      for (int i = 0; i < 2; i++)
#pragma unroll
        for (int r = 0; r < 4; r++)
          rsb[wn * 128 + wm * 32 + i * 16 + l4 * 4 + r] = rsum[i][r];
    }
    __syncthreads();
#pragma unroll
    for (int i = 0; i < 2; i++)
#pragma unroll
      for (int r = 0; r < 4; r++) {
        int rl = wm * 32 + i * 16 + l4 * 4 + r;
        invl[i][r] = 1.0f / (rsb[rl] + rsb[128 + rl]);
      }

    // ================= sweep 2: column sums =================
    for (int ci = 0; ci < nch; ci++) {
      __syncthreads();
#pragma unroll
      for (int cc = 0; cc < 2; cc++) {
        int c = cc * 512 + tid;
        int r = c >> 3, k8 = c & 7;
        int so = r * 64 + ((k8 ^ (r & 7)) * 8);
        size_t ga = ((size_t)(bh * TT + ci * 128 + r)) * DD + k8 * 8;
        *reinterpret_cast<bf16x8*>(&Khs[so]) = *reinterpret_cast<const bf16x8*>(&Kh[ga]);
        *reinterpret_cast<bf16x8*>(&Kls[so]) = *reinterpret_cast<const bf16x8*>(&Kl[ga]);
      }
      __syncthreads();
      f32x4 acc[2][4] = {};
#pragma unroll
      for (int ks = 0; ks < 2; ks++) {
        bf16x8 ah[2], al_[2];
#pragma unroll
        for (int i = 0; i < 2; i++) {
          int ar = wm * 32 + i * 16 + l15;
          int off = ar * 64 + (((ks * 4 + l4) ^ (ar & 7)) * 8);
          ah[i]  = *reinterpret_cast<const bf16x8*>(&Qhs[off]);
          al_[i] = *reinterpret_cast<const bf16x8*>(&Qls[off]);
        }
#pragma unroll
        for (int j = 0; j < 4; j++) {
          int br = wn * 64 + j * 16 + l15;
          int off = br * 64 + (((ks * 4 + l4) ^ (br & 7)) * 8);
          bf16x8 bh_ = *reinterpret_cast<const bf16x8*>(&Khs[off]);
          bf16x8 bl_ = *reinterpret_cast<const bf16x8*>(&Kls[off]);
#pragma unroll
          for (int i = 0; i < 2; i++) {
            acc[i][j] = __builtin_amdgcn_mfma_f32_16x16x32_bf16(ah[i], bh_, acc[i][j], 0, 0, 0);
            acc[i][j] = __builtin_amdgcn_mfma_f32_16x16x32_bf16(ah[i], bl_, acc[i][j], 0, 0, 0);
            acc[i][j] = __builtin_amdgcn_mfma_f32_16x16x32_bf16(al_[i], bh_, acc[i][j], 0, 0, 0);
          }
        }
      }
      const bool diag = (ci == rt);
      float cp[4];
#pragma unroll
      for (int j = 0; j < 4; j++) cp[j] = 0.f;
#pragma unroll
      for (int i = 0; i < 2; i++)
#pragma unroll
        for (int r = 0; r < 4; r++) {
          int row = row0 + wm * 32 + i * 16 + l4 * 4 + r;
          float il = invl[i][r];
#pragma unroll
          for (int j = 0; j < 4; j++) {
            int key = ci * 128 + wn * 64 + j * 16 + l15;
            float p = __expf(acc[i][j][r] * QSCALE) * il;
            if (diag && key > row) p = 0.f;
            cp[j] += p;
          }
        }
      // reduce over rows: across l4 groups
#pragma unroll
      for (int j = 0; j < 4; j++) {
        float v = cp[j];
        v += __shfl_xor(v, 16); v += __shfl_xor(v, 32);
        cp[j] = v;
      }
      __syncthreads();   // K frag reads done -> alias Khs as csw
      if (l4 == 0) {
#pragma unroll
        for (int j = 0; j < 4; j++)
          csw[w * 128 + wn * 64 + j * 16 + l15] = cp[j];
      }
      __syncthreads();
      if (tid < 128) {
        int wnc = tid >> 6;
        float s = csw[(0 * 2 + wnc) * 128 + tid] + csw[(1 * 2 + wnc) * 128 + tid] +
                  csw[(2 * 2 + wnc) * 128 + tid] + csw[(3 * 2 + wnc) * 128 + tid];
        size_t pi = ((size_t)(bh * 8 + pairid)) * 2048 + ci * 128 + tid;
        bool wr = (half == 0) || (ci > pairid);
        part[pi] = wr ? s : (part[pi] + s);
      }
    }
  }
}

// ---------------- Top-K select (exact, ties -> smallest index) + gather ----------------
__global__ __launch_bounds__(256) void topk_gather_kernel(
    const float* __restrict__ part,
    const unsigned short* __restrict__ Kh, const unsigned short* __restrict__ Kl,
    const float* __restrict__ V,
    float* __restrict__ Kk, float* __restrict__ Vk)
{
  const int bh = blockIdx.x, tid = threadIdx.x;
  const int lane = tid & 63, w = tid >> 6;
  __shared__ int redi[4];
  __shared__ int stot;
  __shared__ int base[256];
  __shared__ int idxb[KKEEP];
  unsigned u[8];
#pragma unroll
  for (int k = 0; k < 8; k++) {
    int e = tid * 8 + k;
    float s = 0.f;
#pragma unroll
    for (int p = 0; p < 8; p++)
      if (e < (16 - p) * 128) s += part[((size_t)(bh * 8 + p)) * 2048 + e];
    float v = (e >= TT - REC) ? 3.0e3f : s;
    u[k] = __float_as_uint(v);
  }
  unsigned lo = 0u, hi = 0x7f800000u;
  for (int it = 0; it < 31; it++) {
    unsigned mid = lo + ((hi - lo + 1) >> 1);
    int c = 0;
#pragma unroll
    for (int k = 0; k < 8; k++) c += (u[k] >= mid) ? 1 : 0;
#pragma unroll
    for (int off = 1; off <= 32; off <<= 1) c += __shfl_xor(c, off);
    if (lane == 0) redi[w] = c;
    __syncthreads();
    int tot = redi[0] + redi[1] + redi[2] + redi[3];
    if (tot >= KKEEP) lo = mid; else hi = mid - 1;
    __syncthreads();
  }
  const unsigned vstar = lo;
  int cgt = 0, ceq = 0;
#pragma unroll
  for (int k = 0; k < 8; k++) { cgt += (u[k] > vstar) ? 1 : 0; ceq += (u[k] == vstar) ? 1 : 0; }
  base[tid] = cgt; __syncthreads();
  if (tid == 0) {
    int run = 0;
    for (int i = 0; i < 256; i++) { int t = base[i]; base[i] = run; run += t; }
    stot = run;
  }
  __syncthreads();
  int off1 = base[tid];
#pragma unroll
  for (int k = 0; k < 8; k++)
    if (u[k] > vstar) idxb[off1++] = tid * 8 + k;
  __syncthreads();
  base[tid] = ceq; __syncthreads();
  if (tid == 0) {
    int run = 0;
    for (int i = 0; i < 256; i++) { int t = base[i]; base[i] = run; run += t; }
  }
  __syncthreads();
  int off2 = stot + base[tid];
#pragma unroll
  for (int k = 0; k < 8; k++)
    if (u[k] == vstar) { if (off2 < KKEEP) idxb[off2] = tid * 8 + k; off2++; }
  __syncthreads();
  // gather K (reconstruct f32 = hi + lo), zero-padded to KPAD rows
  for (int f = tid; f < KPAD * 8; f += 256) {
    int kk = f >> 3, c8 = f & 7;
    float o[8];
#pragma unroll
    for (int j = 0; j < 8; j++) o[j] = 0.f;
    if (kk < KKEEP) {
      int sr = idxb[kk];
      bf16x8 hv = *reinterpret_cast<const bf16x8*>(&Kh[((size_t)(bh * TT + sr)) * DD + c8 * 8]);
      bf16x8 lv = *reinterpret_cast<const bf16x8*>(&Kl[((size_t)(bh * TT + sr)) * DD + c8 * 8]);
#pragma unroll
      for (int j = 0; j < 8; j++)
        o[j] = bf_up((unsigned short)hv[j]) + bf_up((unsigned short)lv[j]);
    }
    size_t db = ((size_t)(bh * KPAD + kk)) * DD + c8 * 8;
    *reinterpret_cast<float4*>(&Kk[db])     = make_float4(o[0], o[1], o[2], o[3]);
    *reinterpret_cast<float4*>(&Kk[db + 4]) = make_float4(o[4], o[5], o[6], o[7]);
  }
  for (int f = tid; f < KPAD * 16; f += 256) {
    int kk = f >> 4, c4 = f & 15;
    float4 vv = make_float4(0.f, 0.f, 0.f, 0.f);
    if (kk < KKEEP) {
      int sr = idxb[kk];
      vv = *reinterpret_cast<const float4*>(&V[((size_t)(bh * TT + sr)) * DD + c4 * 4]);
    }
    *reinterpret_cast<float4*>(&Vk[((size_t)(bh * KPAD + kk)) * DD + c4 * 4]) = vv;
  }
}

// ---------------- Fused pass-2 attention over pruned keys ----------------
__global__ __launch_bounds__(256) void attn2_kernel(
    const unsigned short* __restrict__ Qh, const unsigned short* __restrict__ Ql,
    const float* __restrict__ Kk, const float* __restrict__ Vk,
    unsigned short* __restrict__ AOh, unsigned short* __restrict__ AOl)
{
  const int rt = blockIdx.x, bh = blockIdx.y;
  const int tid = threadIdx.x;
  const int tx = tid & 15, ty = tid >> 4;
  __shared__ float4 Qs[64 * 16];
  __shared__ float4 KVs[64 * 16];
  __shared__ float4 Ps[64 * 16];
  const int row0 = rt * 64;
  // stage Q tile (reconstruct f32 from hi/lo planes)
#pragma unroll
  for (int it = 0; it < 2; it++) {
    int idx = it * 256 + tid;
    int r = idx >> 3, k8 = idx & 7;
    size_t ga = ((size_t)(bh * TT + row0 + r)) * DD + k8 * 8;
    bf16x8 hv = *reinterpret_cast<const bf16x8*>(&Qh[ga]);
    bf16x8 lv = *reinterpret_cast<const bf16x8*>(&Ql[ga]);
#pragma unroll
    for (int j = 0; j < 8; j++) {
      int kk = k8 * 8 + j;
      float f = bf_up((unsigned short)hv[j]) + bf_up((unsigned short)lv[j]);
      ((float*)&Qs[kk * 16 + ((r >> 2) ^ ((kk >> 2) & 7))])[r & 3] = f;
    }
  }
  float o[4][4];
  float rsum[4];
#pragma unroll
  for (int i = 0; i < 4; i++) {
    rsum[i] = 0.f;
#pragma unroll
    for (int j = 0; j < 4; j++) o[i][j] = 0.f;
  }
  for (int ci = 0; ci < 7; ci++) {
    __syncthreads();
#pragma unroll
    for (int it = 0; it < 4; it++) {
      int idx = it * 256 + tid;
      int r = idx >> 4, c4 = idx & 15;
      float4 v = *reinterpret_cast<const float4*>(&Kk[((size_t)(bh * KPAD + ci * 64 + r)) * DD + c4 * 4]);
      const float* sv = (const float*)&v;
#pragma unroll
      for (int j = 0; j < 4; j++) {
        int kk = c4 * 4 + j;
        ((float*)&KVs[kk * 16 + ((r >> 2) ^ ((kk >> 2) & 7))])[r & 3] = sv[j];
      }
    }
    __syncthreads();
    float acc[4][4];
#pragma unroll
    for (int i = 0; i < 4; i++)
#pragma unroll
      for (int j = 0; j < 4; j++) acc[i][j] = 0.f;
#pragma unroll 8
    for (int kk = 0; kk < 64; kk++) {
      const int e = (kk >> 2) & 7;
      float4 a = Qs[kk * 16 + (ty ^ e)];
      float4 b = KVs[kk * 16 + (tx ^ e)];
      float av[4] = {a.x, a.y, a.z, a.w};
      float bv[4] = {b.x, b.y, b.z, b.w};
#pragma unroll
      for (int i = 0; i < 4; i++)
#pragma unroll
        for (int j = 0; j < 4; j++)
          acc[i][j] = fmaf(av[i], bv[j], acc[i][j]);
    }
    float p[4][4];
#pragma unroll
    for (int i = 0; i < 4; i++)
#pragma unroll
      for (int j = 0; j < 4; j++) {
        float pp = __expf(acc[i][j] * QSCALE);
        if (ci * 64 + tx * 4 + j >= KKEEP) pp = 0.f;
        p[i][j] = pp;
        rsum[i] += pp;
      }
    __syncthreads();
#pragma unroll
    for (int j = 0; j < 4; j++) {
      int kk = tx * 4 + j;
      Ps[kk * 16 + (ty ^ ((kk >> 2) & 7))] = make_float4(p[0][j], p[1][j], p[2][j], p[3][j]);
    }
#pragma unroll
    for (int it = 0; it < 4; it++) {
      int idx = it * 256 + tid;
      int r = idx >> 4, c4 = idx & 15;
      float4 v = *reinterpret_cast<const float4*>(&Vk[((size_t)(bh * KPAD + ci * 64 + r)) * DD + c4 * 4]);
      KVs[r * 16 + c4] = v;
    }
    __syncthreads();
#pragma unroll 8
    for (int kk = 0; kk < 64; kk++) {
      const int e = (kk >> 2) & 7;
      float4 pa = Ps[kk * 16 + (ty ^ e)];
      float4 vv = KVs[kk * 16 + tx];
      float pav[4] = {pa.x, pa.y, pa.z, pa.w};
      float vvv[4] = {vv.x, vv.y, vv.z, vv.w};
#pragma unroll
      for (int i = 0; i < 4; i++)
#pragma unroll
        for (int j = 0; j < 4; j++)
          o[i][j] = fmaf(pav[i], vvv[j], o[i][j]);
    }
  }
  float inv[4];
#pragma unroll
  for (int i = 0; i < 4; i++) {
    float r_ = rsum[i];
#pragma unroll
    for (int off = 1; off <= 8; off <<= 1) r_ += __shfl_xor(r_, off);
    inv[i] = 1.f / r_;
  }
  const int b = bh >> 4, h = bh & 15;
#pragma unroll
  for (int i = 0; i < 4; i++) {
    int row = row0 + ty * 4 + i;
    size_t bb = ((size_t)(b * TT + row)) * EE + h * DD + tx * 4;
    ushort4 hh, ll;
    float x, f;
    x = o[i][0] * inv[i]; hh.x = bf_rn(x); f = bf_up(hh.x); ll.x = bf_rn(x - f);
    x = o[i][1] * inv[i]; hh.y = bf_rn(x); f = bf_up(hh.y); ll.y = bf_rn(x - f);
    x = o[i][2] * inv[i]; hh.z = bf_rn(x); f = bf_up(hh.z); ll.z = bf_rn(x - f);
    x = o[i][3] * inv[i]; hh.w = bf_rn(x); f = bf_up(hh.w); ll.w = bf_rn(x - f);
    *reinterpret_cast<ushort4*>(&AOh[bb]) = hh;
    *reinterpret_cast<ushort4*>(&AOl[bb]) = ll;
  }
}

extern "C" void kernel_launch(void* const* d_in, const int* in_sizes, int n_in,
                              void* d_out, int out_size, void* d_ws, size_t ws_size,
                              hipStream_t stream)
{
  const float* x     = (const float*)d_in[0];
  const float* Wattn = (const float*)d_in[1];
  const float* Wproj = (const float*)d_in[2];
  float* out = (float*)d_out;
  float* ws  = (float*)d_ws;

  const size_t SZQ = (size_t)NBH * TT * DD;            // 4,194,304 elements
  float* Vb   = ws;                                    // f32 V
  float* part = Vb + SZQ;                              // 524,288 f
  float* Kkp  = part + (size_t)NBH * 8 * TT;           // 917,504 f
  float* Vkp  = Kkp + (size_t)NBH * KPAD * DD;         // 917,504 f
  unsigned short* S1 = (unsigned short*)(Vkp + (size_t)NBH * KPAD * DD);
  unsigned short* Qhp = S1;                            // 4 split planes for Q/K
  unsigned short* Qlp = Qhp + SZQ;
  unsigned short* Khp = Qlp + SZQ;
  unsigned short* Klp = Khp + SZQ;
  unsigned short* xh  = Klp + SZQ;                     // x splits (dead after QKV)
  unsigned short* xl  = xh + (size_t)4096 * 1024;
  unsigned short* Wh  = xl + (size_t)4096 * 1024;      // W_attn splits
  unsigned short* Wl  = Wh + (size_t)3072 * 1024;
  unsigned short* AOh = xh;                            // alias
  unsigned short* AOl = xl;
  unsigned short* Ph  = Wh;                            // alias (after QKV GEMM)
  unsigned short* Pl  = Ph + (size_t)1024 * 1024;

  const size_t needB =
      ((size_t)SZQ + (size_t)NBH * 8 * TT + (size_t)2 * NBH * KPAD * DD) * 4 +
      ((size_t)4 * SZQ + (size_t)2 * 4096 * 1024 + (size_t)2 * 3072 * 1024) * 2; // 89,128,960 B
  if (ws_size < needB) return;

  // 0) split x, W_attn into bf16 hi/lo planes
  split_kernel<<<512, 256, 0, stream>>>(x, xh, xl, 4096 * 1024);
  split_kernel<<<512, 256, 0, stream>>>(Wattn, Wh, Wl, 3072 * 1024);
  // 1) QKV projection (MFMA): Q,K -> split planes; V -> f32
  gemm_bf16s_nt<<<dim3(24, 32), 256, 0, stream>>>(xh, xl, Wh, Wl, nullptr,
                                                  Qhp, Qlp, Khp, Klp, Vb, 4096, 3072, 1024, 1);
  // 1b) split W_proj (aliases W_attn splits; stream-ordered after QKV GEMM)
  split_kernel<<<512, 256, 0, stream>>>(Wproj, Ph, Pl, 1024 * 1024);
  // 2) causal softmax column sums (MFMA)
  importance3_kernel<<<dim3(8, NBH), 512, 0, stream>>>(Qhp, Qlp, Khp, Klp, part);
  // 3) exact top-391 + gather (K reconstructed hi+lo; zero-padded to 448)
  topk_gather_kernel<<<NBH, 256, 0, stream>>>(part, Khp, Klp, Vb, Kkp, Vkp);
  // 4) fused pruned-key attention -> split-bf16 AO planes
  attn2_kernel<<<dim3(32, NBH), 256, 0, stream>>>(Qhp, Qlp, Kkp, Vkp, AOh, AOl);
  // 5) output projection (MFMA)
  gemm_bf16s_nt<<<dim3(8, 32), 256, 0, stream>>>(AOh, AOl, Ph, Pl, out,
                                                 nullptr, nullptr, nullptr, nullptr, nullptr,
                                                 4096, 1024, 1024, 0);
}

// Round 5
// 310.438 us; speedup vs baseline: 20.4815x; 1.3206x over previous
//
#include <hip/hip_runtime.h>
#include <hip/hip_bf16.h>

// PrunedKVAttention: B=2,T=2048,E=1024,H=16,D=64,K_KEEP=391,RECENCY=64
// Round 5: global_load_lds staging everywhere; attn2 -> f16 MFMA (swapped
// QK^T, in-register P^T shuffle assembly, single pass). Deterministic.

#define TT 2048
#define EE 1024
#define HH 16
#define DD 64
#define KKEEP 391
#define REC 64
#define NBH 32
#define QSCALE 0.125f
#define KPAD 448

typedef short bf16x8 __attribute__((ext_vector_type(8)));
typedef _Float16 f16x8 __attribute__((ext_vector_type(8)));
typedef float f32x4 __attribute__((ext_vector_type(4)));

static __device__ inline unsigned short bf_rn(float x) {
  unsigned u = __float_as_uint(x);
  unsigned r = u + 0x7fffu + ((u >> 16) & 1u);
  return (unsigned short)(r >> 16);
}
static __device__ inline float bf_up(unsigned short h) {
  return __uint_as_float((unsigned)h << 16);
}
static __device__ inline unsigned pkf16(float a, float b) {
  union { _Float16 h[2]; unsigned u; } t;
  t.h[0] = (_Float16)a; t.h[1] = (_Float16)b; return t.u;
}
// async global->LDS, 16B per lane; LDS dest = wave-uniform base + lane*16
static __device__ inline void glds16(const void* g, void* l) {
  __builtin_amdgcn_global_load_lds(
      (const __attribute__((address_space(1))) void*)g,
      (__attribute__((address_space(3))) void*)l, 16, 0, 0);
}

// ---------------- split f32 -> (hi, lo) bf16 planes ----------------
__global__ __launch_bounds__(256) void split_kernel(
    const float* __restrict__ src, unsigned short* __restrict__ ho,
    unsigned short* __restrict__ lo_, int n)
{
  int i = (blockIdx.x * 256 + threadIdx.x) * 4;
  const int stride = gridDim.x * 1024;
  for (; i < n; i += stride) {
    float4 v = *reinterpret_cast<const float4*>(&src[i]);
    ushort4 hh, ll;
    float f;
    hh.x = bf_rn(v.x); f = bf_up(hh.x); ll.x = bf_rn(v.x - f);
    hh.y = bf_rn(v.y); f = bf_up(hh.y); ll.y = bf_rn(v.y - f);
    hh.z = bf_rn(v.z); f = bf_up(hh.z); ll.z = bf_rn(v.z - f);
    hh.w = bf_rn(v.w); f = bf_up(hh.w); ll.w = bf_rn(v.w - f);
    *reinterpret_cast<ushort4*>(&ho[i]) = hh;
    *reinterpret_cast<ushort4*>(&lo_[i]) = ll;
  }
}

// ---------------- MFMA GEMM (NT): C[M,N] = A[M,K]*B[N,K]^T ----------------
// global_load_lds staging, pre-swizzled source (kb = pb ^ ((r>>1)&3)).
__global__ __launch_bounds__(256) void gemm_bf16s_nt(
    const unsigned short* __restrict__ Ah, const unsigned short* __restrict__ Al,
    const unsigned short* __restrict__ Bh, const unsigned short* __restrict__ Bl,
    float* __restrict__ Cc, unsigned short* __restrict__ Qho, unsigned short* __restrict__ Qlo,
    unsigned short* __restrict__ Kho, unsigned short* __restrict__ Klo,
    float* __restrict__ Vo, int M, int N, int Kd, int mode)
{
  __shared__ __align__(16) unsigned short Ahs[128 * 32];
  __shared__ __align__(16) unsigned short Als[128 * 32];
  __shared__ __align__(16) unsigned short Bhs[128 * 32];
  __shared__ __align__(16) unsigned short Bls[128 * 32];
  const int tid = threadIdx.x;
  const int m0 = blockIdx.y * 128, n0 = blockIdx.x * 128;
  const int w = tid >> 6, lane = tid & 63;
  const int wm = w >> 1, wn = w & 1;
  const int l15 = lane & 15, l4 = lane >> 4;

  // per-lane staging constants (2 segments/wave/plane)
  size_t gA[2], gB[2]; int ldso[2];
#pragma unroll
  for (int s = 0; s < 2; s++) {
    int seg = w * 2 + s;
    int r = seg * 16 + (lane >> 2);
    int kb = (lane & 3) ^ ((r >> 1) & 3);
    gA[s] = (size_t)(m0 + r) * Kd + kb * 8;
    gB[s] = (size_t)(n0 + r) * Kd + kb * 8;
    ldso[s] = seg * 512;
  }

  f32x4 acc[4][4] = {};

  for (int k0 = 0; k0 < Kd; k0 += 32) {
#pragma unroll
    for (int s = 0; s < 2; s++) {
      glds16(&Ah[gA[s] + k0], &Ahs[ldso[s]]);
      glds16(&Al[gA[s] + k0], &Als[ldso[s]]);
      glds16(&Bh[gB[s] + k0], &Bhs[ldso[s]]);
      glds16(&Bl[gB[s] + k0], &Bls[ldso[s]]);
    }
    __syncthreads();
    bf16x8 ah[4], al[4], bh[4], bl[4];
#pragma unroll
    for (int i = 0; i < 4; i++) {
      int ar = wm * 64 + i * 16 + l15;
      int aoff = ar * 32 + ((l4 ^ ((ar >> 1) & 3)) * 8);
      ah[i] = *reinterpret_cast<const bf16x8*>(&Ahs[aoff]);
      al[i] = *reinterpret_cast<const bf16x8*>(&Als[aoff]);
      int br = wn * 64 + i * 16 + l15;
      int boff = br * 32 + ((l4 ^ ((br >> 1) & 3)) * 8);
      bh[i] = *reinterpret_cast<const bf16x8*>(&Bhs[boff]);
      bl[i] = *reinterpret_cast<const bf16x8*>(&Bls[boff]);
    }
#pragma unroll
    for (int i = 0; i < 4; i++)
#pragma unroll
      for (int j = 0; j < 4; j++) {
        acc[i][j] = __builtin_amdgcn_mfma_f32_16x16x32_bf16(ah[i], bh[j], acc[i][j], 0, 0, 0);
        acc[i][j] = __builtin_amdgcn_mfma_f32_16x16x32_bf16(ah[i], bl[j], acc[i][j], 0, 0, 0);
        acc[i][j] = __builtin_amdgcn_mfma_f32_16x16x32_bf16(al[i], bh[j], acc[i][j], 0, 0, 0);
      }
    __syncthreads();
  }

  if (mode == 0) {
#pragma unroll
    for (int i = 0; i < 4; i++) {
      int mrow0 = m0 + wm * 64 + i * 16 + l4 * 4;
#pragma unroll
      for (int j = 0; j < 4; j++) {
        int ncol = n0 + wn * 64 + j * 16 + l15;
#pragma unroll
        for (int r = 0; r < 4; r++)
          Cc[(size_t)(mrow0 + r) * N + ncol] = acc[i][j][r];
      }
    }
  } else {
#pragma unroll
    for (int j = 0; j < 4; j++) {
      int n = n0 + wn * 64 + j * 16 + l15;
      int p = n >> 10, rr = n & 1023;
      int h = rr >> 6, d0 = rr & 63;
#pragma unroll
      for (int i = 0; i < 4; i++) {
        int mrow0 = m0 + wm * 64 + i * 16 + l4 * 4;
#pragma unroll
        for (int r = 0; r < 4; r++) {
          int m = mrow0 + r;
          int b = m >> 11, t = m & 2047;
          size_t idx = ((size_t)((b * HH + h) * TT + t)) * DD + d0;
          float v = acc[i][j][r];
          if (p == 2) {
            Vo[idx] = v;
          } else {
            unsigned short hi_ = bf_rn(v);
            unsigned short lo2 = bf_rn(v - bf_up(hi_));
            if (p == 0) { Qho[idx] = hi_; Qlo[idx] = lo2; }
            else        { Kho[idx] = hi_; Klo[idx] = lo2; }
          }
        }
      }
    }
  }
}

// ---------------- Importance (MFMA): causal softmax column sums ----------------
__global__ __launch_bounds__(512) void importance3_kernel(
    const unsigned short* __restrict__ Qh, const unsigned short* __restrict__ Ql,
    const unsigned short* __restrict__ Kh, const unsigned short* __restrict__ Kl,
    float* __restrict__ part)
{
  const int pairid = blockIdx.x, bh = blockIdx.y;
  const int tid = threadIdx.x;
  const int w = tid >> 6, lane = tid & 63;
  const int wm = w >> 1, wn = w & 1;
  const int l15 = lane & 15, l4 = lane >> 4;
  __shared__ __align__(16) unsigned short Qhs[128 * 64];
  __shared__ __align__(16) unsigned short Qls[128 * 64];
  __shared__ __align__(16) unsigned short Khs[128 * 64];
  __shared__ __align__(16) unsigned short Kls[128 * 64];
  float* csw = (float*)Khs;   // [8][128] col-sum slab (barrier-fenced alias)
  float* rsb = (float*)Kls;   // [2][128] row-sum exchange (barrier-fenced alias)

  // per-lane K staging constants (2 segs/wave/plane, 16 segs total)
  int krow[2], kkb[2], klds[2];
#pragma unroll
  for (int s = 0; s < 2; s++) {
    int seg = w * 2 + s;
    int r = seg * 8 + (lane >> 3);
    int k8 = lane & 7;
    krow[s] = r; kkb[s] = k8 ^ (r & 7); klds[s] = seg * 512;
  }

  for (int half = 0; half < 2; half++) {
    const int rt = half ? (15 - pairid) : pairid;
    const int row0 = rt * 128;
    const int nch = rt + 1;
    __syncthreads();
    // stage Q tile (128 rows x 64 dims), swizzled chunk layout
#pragma unroll
    for (int cc = 0; cc < 2; cc++) {
      int c = cc * 512 + tid;
      int r = c >> 3, k8 = c & 7;
      int so = r * 64 + ((k8 ^ (r & 7)) * 8);
      size_t ga = ((size_t)(bh * TT + row0 + r)) * DD + k8 * 8;
      *reinterpret_cast<bf16x8*>(&Qhs[so]) = *reinterpret_cast<const bf16x8*>(&Qh[ga]);
      *reinterpret_cast<bf16x8*>(&Qls[so]) = *reinterpret_cast<const bf16x8*>(&Ql[ga]);
    }

    float rsum[2][4];
#pragma unroll
    for (int i = 0; i < 2; i++)
#pragma unroll
      for (int r = 0; r < 4; r++) rsum[i][r] = 0.f;
    float invl[2][4];

    for (int sweep = 0; sweep < 2; sweep++) {
      for (int ci = 0; ci < nch; ci++) {
        __syncthreads();
#pragma unroll
        for (int s = 0; s < 2; s++) {
          size_t ga = ((size_t)(bh * TT + ci * 128 + krow[s])) * DD + kkb[s] * 8;
          glds16(&Kh[ga], &Khs[klds[s]]);
          glds16(&Kl[ga], &Kls[klds[s]]);
        }
        __syncthreads();
        f32x4 acc[2][4] = {};
#pragma unroll
        for (int ks = 0; ks < 2; ks++) {
          bf16x8 ah[2], al_[2];
#pragma unroll
          for (int i = 0; i < 2; i++) {
            int ar = wm * 32 + i * 16 + l15;
            int off = ar * 64 + (((ks * 4 + l4) ^ (ar & 7)) * 8);
            ah[i]  = *reinterpret_cast<const bf16x8*>(&Qhs[off]);
            al_[i] = *reinterpret_cast<const bf16x8*>(&Qls[off]);
          }
#pragma unroll
          for (int j = 0; j < 4; j++) {
            int br = wn * 64 + j * 16 + l15;
            int off = br * 64 + (((ks * 4 + l4) ^ (br & 7)) * 8);
            bf16x8 bh_ = *reinterpret_cast<const bf16x8*>(&Khs[off]);
            bf16x8 bl_ = *reinterpret_cast<const bf16x8*>(&Kls[off]);
#pragma unroll
            for (int i = 0; i < 2; i++) {
              acc[i][j] = __builtin_amdgcn_mfma_f32_16x16x32_bf16(ah[i], bh_, acc[i][j], 0, 0, 0);
              acc[i][j] = __builtin_amdgcn_mfma_f32_16x16x32_bf16(ah[i], bl_, acc[i][j], 0, 0, 0);
              acc[i][j] = __builtin_amdgcn_mfma_f32_16x16x32_bf16(al_[i], bh_, acc[i][j], 0, 0, 0);
            }
          }
        }
        const bool diag = (ci == rt);
        if (sweep == 0) {
#pragma unroll
          for (int i = 0; i < 2; i++)
#pragma unroll
            for (int r = 0; r < 4; r++) {
              int row = row0 + wm * 32 + i * 16 + l4 * 4 + r;
              float s = 0.f;
#pragma unroll
              for (int j = 0; j < 4; j++) {
                int key = ci * 128 + wn * 64 + j * 16 + l15;
                float p = __expf(acc[i][j][r] * QSCALE);
                if (diag && key > row) p = 0.f;
                s += p;
              }
              rsum[i][r] += s;
            }
        } else {
          float cp[4];
#pragma unroll
          for (int j = 0; j < 4; j++) cp[j] = 0.f;
#pragma unroll
          for (int i = 0; i < 2; i++)
#pragma unroll
            for (int r = 0; r < 4; r++) {
              int row = row0 + wm * 32 + i * 16 + l4 * 4 + r;
              float il = invl[i][r];
#pragma unroll
              for (int j = 0; j < 4; j++) {
                int key = ci * 128 + wn * 64 + j * 16 + l15;
                float p = __expf(acc[i][j][r] * QSCALE) * il;
                if (diag && key > row) p = 0.f;
                cp[j] += p;
              }
            }
#pragma unroll
          for (int j = 0; j < 4; j++) {
            float v = cp[j];
            v += __shfl_xor(v, 16); v += __shfl_xor(v, 32);
            cp[j] = v;
          }
          __syncthreads();   // K frag reads done -> alias Khs as csw
          if (l4 == 0) {
#pragma unroll
            for (int j = 0; j < 4; j++)
              csw[w * 128 + wn * 64 + j * 16 + l15] = cp[j];
          }
          __syncthreads();
          if (tid < 128) {
            int wnc = tid >> 6;
            float s = csw[(0 * 2 + wnc) * 128 + tid] + csw[(1 * 2 + wnc) * 128 + tid] +
                      csw[(2 * 2 + wnc) * 128 + tid] + csw[(3 * 2 + wnc) * 128 + tid];
            size_t pi = ((size_t)(bh * 8 + pairid)) * 2048 + ci * 128 + tid;
            bool wr = (half == 0) || (ci > pairid);
            part[pi] = wr ? s : (part[pi] + s);
          }
        }
      }
      if (sweep == 0) {
#pragma unroll
        for (int i = 0; i < 2; i++)
#pragma unroll
          for (int r = 0; r < 4; r++) {
            float v = rsum[i][r];
            v += __shfl_xor(v, 1); v += __shfl_xor(v, 2);
            v += __shfl_xor(v, 4); v += __shfl_xor(v, 8);
            rsum[i][r] = v;
          }
        __syncthreads();   // K frag reads done -> safe to alias Kls as rsb
        if (l15 == 0) {
#pragma unroll
          for (int i = 0; i < 2; i++)
#pragma unroll
            for (int r = 0; r < 4; r++)
              rsb[wn * 128 + wm * 32 + i * 16 + l4 * 4 + r] = rsum[i][r];
        }
        __syncthreads();
#pragma unroll
        for (int i = 0; i < 2; i++)
#pragma unroll
          for (int r = 0; r < 4; r++) {
            int rl = wm * 32 + i * 16 + l4 * 4 + r;
            invl[i][r] = 1.0f / (rsb[rl] + rsb[128 + rl]);
          }
      }
    }
  }
}

// ---------------- Top-K select + gather (K f16, V f16-transposed) ----------------
__global__ __launch_bounds__(256) void topk_gather_kernel(
    const float* __restrict__ part,
    const unsigned short* __restrict__ Kh, const unsigned short* __restrict__ Kl,
    const float* __restrict__ V,
    unsigned short* __restrict__ Kf, unsigned short* __restrict__ Vt)
{
  const int bh = blockIdx.x, tid = threadIdx.x;
  const int lane = tid & 63, w = tid >> 6;
  __shared__ int redi[4];
  __shared__ int stot;
  __shared__ int base[256];
  __shared__ int idxb[KKEEP];
  unsigned u[8];
#pragma unroll
  for (int k = 0; k < 8; k++) {
    int e = tid * 8 + k;
    float s = 0.f;
#pragma unroll
    for (int p = 0; p < 8; p++)
      if (e < (16 - p) * 128) s += part[((size_t)(bh * 8 + p)) * 2048 + e];
    float v = (e >= TT - REC) ? 3.0e3f : s;
    u[k] = __float_as_uint(v);
  }
  unsigned lo = 0u, hi = 0x7f800000u;
  for (int it = 0; it < 31; it++) {
    unsigned mid = lo + ((hi - lo + 1) >> 1);
    int c = 0;
#pragma unroll
    for (int k = 0; k < 8; k++) c += (u[k] >= mid) ? 1 : 0;
#pragma unroll
    for (int off = 1; off <= 32; off <<= 1) c += __shfl_xor(c, off);
    if (lane == 0) redi[w] = c;
    __syncthreads();
    int tot = redi[0] + redi[1] + redi[2] + redi[3];
    if (tot >= KKEEP) lo = mid; else hi = mid - 1;
    __syncthreads();
  }
  const unsigned vstar = lo;
  int cgt = 0, ceq = 0;
#pragma unroll
  for (int k = 0; k < 8; k++) { cgt += (u[k] > vstar) ? 1 : 0; ceq += (u[k] == vstar) ? 1 : 0; }
  base[tid] = cgt; __syncthreads();
  if (tid == 0) {
    int run = 0;
    for (int i = 0; i < 256; i++) { int t = base[i]; base[i] = run; run += t; }
    stot = run;
  }
  __syncthreads();
  int off1 = base[tid];
#pragma unroll
  for (int k = 0; k < 8; k++)
    if (u[k] > vstar) idxb[off1++] = tid * 8 + k;
  __syncthreads();
  base[tid] = ceq; __syncthreads();
  if (tid == 0) {
    int run = 0;
    for (int i = 0; i < 256; i++) { int t = base[i]; base[i] = run; run += t; }
  }
  __syncthreads();
  int off2 = stot + base[tid];
#pragma unroll
  for (int k = 0; k < 8; k++)
    if (u[k] == vstar) { if (off2 < KKEEP) idxb[off2] = tid * 8 + k; off2++; }
  __syncthreads();
  // K -> f16 plane [bh][KPAD][64], zero-padded
  for (int f = tid; f < KPAD * 8; f += 256) {
    int kk = f >> 3, c8 = f & 7;
    union { _Float16 h[8]; uint4 v; } o;
#pragma unroll
    for (int j = 0; j < 8; j++) o.h[j] = (_Float16)0.f;
    if (kk < KKEEP) {
      int sr = idxb[kk];
      bf16x8 hv = *reinterpret_cast<const bf16x8*>(&Kh[((size_t)(bh * TT + sr)) * DD + c8 * 8]);
      bf16x8 lv = *reinterpret_cast<const bf16x8*>(&Kl[((size_t)(bh * TT + sr)) * DD + c8 * 8]);
#pragma unroll
      for (int j = 0; j < 8; j++)
        o.h[j] = (_Float16)(bf_up((unsigned short)hv[j]) + bf_up((unsigned short)lv[j]));
    }
    *reinterpret_cast<uint4*>(&Kf[((size_t)(bh * KPAD) + kk) * DD + c8 * 8]) = o.v;
  }
  // V -> f16 transposed plane [bh][64][KPAD], zero-padded
  for (int f = tid; f < KPAD * 8; f += 256) {
    int kk = f >> 3, d8 = f & 7;
    float vv[8];
#pragma unroll
    for (int j = 0; j < 8; j++) vv[j] = 0.f;
    if (kk < KKEEP) {
      int sr = idxb[kk];
      float4 a = *reinterpret_cast<const float4*>(&V[((size_t)(bh * TT + sr)) * DD + d8 * 8]);
      float4 b = *reinterpret_cast<const float4*>(&V[((size_t)(bh * TT + sr)) * DD + d8 * 8 + 4]);
      vv[0] = a.x; vv[1] = a.y; vv[2] = a.z; vv[3] = a.w;
      vv[4] = b.x; vv[5] = b.y; vv[6] = b.z; vv[7] = b.w;
    }
#pragma unroll
    for (int j = 0; j < 8; j++) {
      union { _Float16 h; unsigned short s; } t;
      t.h = (_Float16)vv[j];
      Vt[((size_t)(bh * DD) + d8 * 8 + j) * KPAD + kk] = t.s;
    }
  }
}

// ---------------- Pass-2 attention: f16 MFMA, swapped QK^T ----------------
// grid (32 row-tiles of 64, 32 bh), 256 thr = 4 waves, wave w owns q rows w*16..+16.
__global__ __launch_bounds__(256) void attn3_kernel(
    const unsigned short* __restrict__ Qh, const unsigned short* __restrict__ Ql,
    const unsigned short* __restrict__ Kf, const unsigned short* __restrict__ Vt,
    unsigned short* __restrict__ AOh, unsigned short* __restrict__ AOl)
{
  const int rt = blockIdx.x, bh = blockIdx.y;
  const int tid = threadIdx.x;
  const int w = tid >> 6, lane = tid & 63;
  const int l15 = lane & 15, l4 = lane >> 4;
  __shared__ __align__(16) unsigned short Qs[64 * 64];  // f16 bits
  __shared__ __align__(16) unsigned short Ks[64 * 64];
  __shared__ __align__(16) unsigned short Vs[64 * 64];
  __shared__ float LDSo[4][64][16];
  const int row0 = rt * 64;

  // stage Q (f16) from split-bf16 planes
#pragma unroll
  for (int it = 0; it < 2; it++) {
    int idx = it * 256 + tid;
    int r = idx >> 3, k8 = idx & 7;
    size_t ga = ((size_t)(bh * TT + row0 + r)) * DD + k8 * 8;
    bf16x8 hv = *reinterpret_cast<const bf16x8*>(&Qh[ga]);
    bf16x8 lv = *reinterpret_cast<const bf16x8*>(&Ql[ga]);
    union { _Float16 h[8]; uint4 v; } q16;
#pragma unroll
    for (int j = 0; j < 8; j++)
      q16.h[j] = (_Float16)(bf_up((unsigned short)hv[j]) + bf_up((unsigned short)lv[j]));
    *reinterpret_cast<uint4*>(&Qs[r * 64 + ((k8 ^ (r & 7)) * 8)]) = q16.v;
  }
  __syncthreads();
  // hoist Q B-fragments (wave's 16 q rows)
  f16x8 bq[2];
#pragma unroll
  for (int ks = 0; ks < 2; ks++) {
    int br = w * 16 + l15;
    bq[ks] = *reinterpret_cast<const f16x8*>(&Qs[br * 64 + (((ks * 4 + l4) ^ (br & 7)) * 8)]);
  }

  // per-lane staging constants for K/Vt (2 segs/wave/plane)
  int srow[2], skb[2], slds[2];
#pragma unroll
  for (int s = 0; s < 2; s++) {
    int seg = w * 2 + s;
    int r = seg * 8 + (lane >> 3);
    int k8 = lane & 7;
    srow[s] = r; skb[s] = k8 ^ (r & 7); slds[s] = seg * 512;
  }

  f32x4 acc_o[4] = {};
  float rsum = 0.f;

  for (int ci = 0; ci < 7; ci++) {
    __syncthreads();   // prev chunk's LDS reads done
#pragma unroll
    for (int s = 0; s < 2; s++) {
      glds16(&Kf[((size_t)(bh * KPAD) + ci * 64 + srow[s]) * DD + skb[s] * 8], &Ks[slds[s]]);
      glds16(&Vt[((size_t)(bh * DD) + srow[s]) * KPAD + ci * 64 + skb[s] * 8], &Vs[slds[s]]);
    }
    __syncthreads();
    // QK^T swapped: C[key][q]
    f32x4 accs[4] = {};
#pragma unroll
    for (int ks = 0; ks < 2; ks++) {
#pragma unroll
      for (int i = 0; i < 4; i++) {
        int kr = i * 16 + l15;
        f16x8 af = *reinterpret_cast<const f16x8*>(&Ks[kr * 64 + (((ks * 4 + l4) ^ (kr & 7)) * 8)]);
        accs[i] = __builtin_amdgcn_mfma_f32_16x16x32_f16(af, bq[ks], accs[i], 0, 0, 0);
      }
    }
    // P~ = exp(s*scale), masked; accumulate rsum
    float p[4][4];
#pragma unroll
    for (int i = 0; i < 4; i++)
#pragma unroll
      for (int r = 0; r < 4; r++) {
        int gk = ci * 64 + i * 16 + l4 * 4 + r;
        float pp = __expf(accs[i][r] * QSCALE);
        if (gk >= KKEEP) pp = 0.f;
        p[i][r] = pp;
        rsum += pp;
      }
    // pack pairs (f16) for shuffle assembly
    unsigned pkU[4][2];
#pragma unroll
    for (int i = 0; i < 4; i++) {
      pkU[i][0] = pkf16(p[i][0], p[i][1]);
      pkU[i][1] = pkf16(p[i][2], p[i][3]);
    }
    // PV: out^T[d][q] += mfma(V^T rows d, P^T rows q)
#pragma unroll
    for (int ks = 0; ks < 2; ks++) {
      union { f16x8 h; unsigned u[4]; } bp;
#pragma unroll
      for (int wp = 0; wp < 4; wp++) {
        int src = ((l4 & 1) * 2 + (wp >> 1)) * 16 + l15;
        unsigned v0 = (unsigned)__shfl((int)pkU[ks * 2][wp & 1], src);
        unsigned v1 = (unsigned)__shfl((int)pkU[ks * 2 + 1][wp & 1], src);
        bp.u[wp] = (l4 & 2) ? v1 : v0;
      }
#pragma unroll
      for (int i = 0; i < 4; i++) {
        int dr = i * 16 + l15;
        f16x8 av = *reinterpret_cast<const f16x8*>(&Vs[dr * 64 + (((ks * 4 + l4) ^ (dr & 7)) * 8)]);
        acc_o[i] = __builtin_amdgcn_mfma_f32_16x16x32_f16(av, bp.h, acc_o[i], 0, 0, 0);
      }
    }
  }
  // normalize (rsum for q=l15 after cross-l4 reduce) and transpose via LDS
  rsum += __shfl_xor(rsum, 16);
  rsum += __shfl_xor(rsum, 32);
  float inv = 1.0f / rsum;
#pragma unroll
  for (int i = 0; i < 4; i++)
#pragma unroll
    for (int r = 0; r < 4; r++)
      LDSo[w][i * 16 + l4 * 4 + r][l15] = acc_o[i][r] * inv;
  __syncthreads();
  const int b = bh >> 4, h = bh & 15;
#pragma unroll
  for (int uu = 0; uu < 2; uu++) {
    int u = uu * 64 + lane;
    int q = u >> 3, dc = u & 7;
    int row = row0 + w * 16 + q;
    union { unsigned short s[8]; uint4 v; } sh, sl;
#pragma unroll
    for (int j = 0; j < 8; j++) {
      float v = LDSo[w][dc * 8 + j][q];
      unsigned short hh = bf_rn(v);
      sh.s[j] = hh;
      sl.s[j] = bf_rn(v - bf_up(hh));
    }
    size_t addr = ((size_t)(b * TT + row)) * EE + h * DD + dc * 8;
    *reinterpret_cast<uint4*>(&AOh[addr]) = sh.v;
    *reinterpret_cast<uint4*>(&AOl[addr]) = sl.v;
  }
}

extern "C" void kernel_launch(void* const* d_in, const int* in_sizes, int n_in,
                              void* d_out, int out_size, void* d_ws, size_t ws_size,
                              hipStream_t stream)
{
  const float* x     = (const float*)d_in[0];
  const float* Wattn = (const float*)d_in[1];
  const float* Wproj = (const float*)d_in[2];
  float* out = (float*)d_out;
  float* ws  = (float*)d_ws;

  const size_t SZQ = (size_t)NBH * TT * DD;            // 4,194,304 elements
  const size_t SZK = (size_t)NBH * KPAD * DD;          // 917,504
  float* Vb   = ws;                                    // f32 V
  float* part = Vb + SZQ;                              // 524,288 f
  unsigned short* Kf  = (unsigned short*)(part + (size_t)NBH * 8 * TT);
  unsigned short* Vt  = Kf + SZK;
  unsigned short* Qhp = Vt + SZK;
  unsigned short* Qlp = Qhp + SZQ;
  unsigned short* Khp = Qlp + SZQ;
  unsigned short* Klp = Khp + SZQ;
  unsigned short* xh  = Klp + SZQ;                     // x splits (dead after QKV)
  unsigned short* xl  = xh + (size_t)4096 * 1024;
  unsigned short* Wh  = xl + (size_t)4096 * 1024;      // W_attn splits
  unsigned short* Wl  = Wh + (size_t)3072 * 1024;
  unsigned short* AOh = xh;                            // alias
  unsigned short* AOl = xl;
  unsigned short* Ph  = Wh;                            // alias (after QKV GEMM)
  unsigned short* Pl  = Ph + (size_t)1024 * 1024;

  const size_t needB =
      ((size_t)SZQ + (size_t)NBH * 8 * TT) * 4 +
      ((size_t)2 * SZK + (size_t)4 * SZQ + (size_t)2 * 4096 * 1024 + (size_t)2 * 3072 * 1024) * 2;
  if (ws_size < needB) return;   // ~85.5 MB

  // 0) split x, W_attn into bf16 hi/lo planes
  split_kernel<<<512, 256, 0, stream>>>(x, xh, xl, 4096 * 1024);
  split_kernel<<<512, 256, 0, stream>>>(Wattn, Wh, Wl, 3072 * 1024);
  // 1) QKV projection (MFMA): Q,K -> split planes; V -> f32
  gemm_bf16s_nt<<<dim3(24, 32), 256, 0, stream>>>(xh, xl, Wh, Wl, nullptr,
                                                  Qhp, Qlp, Khp, Klp, Vb, 4096, 3072, 1024, 1);
  // 1b) split W_proj (aliases W_attn splits; stream-ordered after QKV GEMM)
  split_kernel<<<512, 256, 0, stream>>>(Wproj, Ph, Pl, 1024 * 1024);
  // 2) causal softmax column sums (MFMA)
  importance3_kernel<<<dim3(8, NBH), 512, 0, stream>>>(Qhp, Qlp, Khp, Klp, part);
  // 3) exact top-391 + gather (K f16 plane, V f16 transposed, zero-padded)
  topk_gather_kernel<<<NBH, 256, 0, stream>>>(part, Khp, Klp, Vb, Kf, Vt);
  // 4) pruned-key attention (f16 MFMA) -> split-bf16 AO planes
  attn3_kernel<<<dim3(32, NBH), 256, 0, stream>>>(Qhp, Qlp, Kf, Vt, AOh, AOl);
  // 5) output projection (MFMA)
  gemm_bf16s_nt<<<dim3(8, 32), 256, 0, stream>>>(AOh, AOl, Ph, Pl, out,
                                                 nullptr, nullptr, nullptr, nullptr, nullptr,
                                                 4096, 1024, 1024, 0);
}